// Round 2
// baseline (3975.946 us; speedup 1.0000x reference)
//
#include <hip/hip_runtime.h>

// Problem dims
#define E_DIM 116
#define NHEAD 4
#define DHEAD 29
#define SEQ 64       // attention axis (the "B" axis of x)
#define NBATCH 512   // batch axis (the "T" axis of x)
#define NTOK 32768   // 64*512
#define DFF_DIM 2048
#define A_DIM 116
#define C_DIM 90
#define HID_DIM 64

// ---------------------------------------------------------------------------
// KA: Y[M,N] = (X[M,116] @ W[N,116]^T) + bias, optional ReLU.
// 64x64 tile, 256 threads, 4x4 register tile, K=116 fully staged (transposed
// in LDS so fragment reads are float4 / ds_read_b128).
// ---------------------------------------------------------------------------
__global__ __launch_bounds__(256) void gemm_k116_kernel(
    const float* __restrict__ X, const float* __restrict__ W,
    const float* __restrict__ bias, float* __restrict__ Y, int N, int RELU) {
  __shared__ __align__(16) float Xs[116][68];
  __shared__ __align__(16) float Ws[116][68];
  const int tid = threadIdx.x;
  const int row0 = blockIdx.x * 64;
  const int col0 = blockIdx.y * 64;

  for (int idx = tid; idx < 64 * 116; idx += 256) {
    int r = idx / 116;
    int c = idx - r * 116;
    Xs[c][r] = X[(size_t)(row0 + r) * 116 + c];
    int jr = col0 + r;
    Ws[c][r] = (jr < N) ? W[(size_t)jr * 116 + c] : 0.f;
  }
  __syncthreads();

  const int ty = tid >> 4, tx = tid & 15;
  float acc[4][4] = {};
#pragma unroll 4
  for (int e = 0; e < 116; ++e) {
    const float4 xv = *reinterpret_cast<const float4*>(&Xs[e][ty * 4]);
    const float4 wv = *reinterpret_cast<const float4*>(&Ws[e][tx * 4]);
    const float xr[4] = {xv.x, xv.y, xv.z, xv.w};
    const float wr[4] = {wv.x, wv.y, wv.z, wv.w};
#pragma unroll
    for (int i = 0; i < 4; ++i)
#pragma unroll
      for (int j = 0; j < 4; ++j) acc[i][j] = fmaf(xr[i], wr[j], acc[i][j]);
  }

#pragma unroll
  for (int i = 0; i < 4; ++i) {
    const int row = row0 + ty * 4 + i;
#pragma unroll
    for (int j = 0; j < 4; ++j) {
      const int col = col0 + tx * 4 + j;
      if (col < N) {
        float v = acc[i][j] + bias[col];
        if (RELU) v = fmaxf(v, 0.f);
        Y[(size_t)row * N + col] = v;
      }
    }
  }
}

// ---------------------------------------------------------------------------
// KB: Xout[tok, 0:116] = LayerNorm( res + X[tok,0:K] @ W[116,K]^T + bias )
// Block covers 64 tokens x full N=116 so LN fuses.  K looped in chunks of 64.
// thread: ty=tid>>4 owns tokens ty*4..ty*4+3 ; tx=tid&15 owns j = tx+16*jj.
// ---------------------------------------------------------------------------
__global__ __launch_bounds__(256) void gemm_res_ln_kernel(
    const float* __restrict__ X, const float* __restrict__ W,
    const float* __restrict__ bias, const float* __restrict__ res,
    const float* __restrict__ g, const float* __restrict__ beta,
    float* __restrict__ Y, int K) {
  __shared__ float Xs[64][65];
  __shared__ float Ws[128][65];
  const int tid = threadIdx.x;
  const int row0 = blockIdx.x * 64;
  const int ty = tid >> 4, tx = tid & 15;
  float acc[4][8] = {};

  for (int k0 = 0; k0 < K; k0 += 64) {
    for (int idx = tid; idx < 64 * 64; idx += 256) {
      int r = idx >> 6, c = idx & 63;
      int kk = k0 + c;
      Xs[r][c] = (kk < K) ? X[(size_t)(row0 + r) * K + kk] : 0.f;
    }
    for (int idx = tid; idx < 128 * 64; idx += 256) {
      int r = idx >> 6, c = idx & 63;
      int kk = k0 + c;
      Ws[r][c] = (r < 116 && kk < K) ? W[(size_t)r * K + kk] : 0.f;
    }
    __syncthreads();
#pragma unroll 4
    for (int e = 0; e < 64; ++e) {
      float xv[4], wv[8];
#pragma unroll
      for (int i = 0; i < 4; ++i) xv[i] = Xs[ty * 4 + i][e];
#pragma unroll
      for (int jj = 0; jj < 8; ++jj) wv[jj] = Ws[tx + 16 * jj][e];
#pragma unroll
      for (int i = 0; i < 4; ++i)
#pragma unroll
        for (int jj = 0; jj < 8; ++jj) acc[i][jj] = fmaf(xv[i], wv[jj], acc[i][jj]);
    }
    __syncthreads();
  }

#pragma unroll
  for (int i = 0; i < 4; ++i) {
    const int tok = row0 + ty * 4 + i;
    float v[8];
    float s = 0.f, s2 = 0.f;
#pragma unroll
    for (int jj = 0; jj < 8; ++jj) {
      const int j = tx + 16 * jj;
      if (j < 116) {
        float t = acc[i][jj] + bias[j] + res[(size_t)tok * 116 + j];
        v[jj] = t;
        s += t;
        s2 += t * t;
      } else {
        v[jj] = 0.f;
      }
    }
    // reduce across the 16 tx-lanes (they own the whole row)
    for (int m = 1; m < 16; m <<= 1) {
      s += __shfl_xor(s, m, 16);
      s2 += __shfl_xor(s2, m, 16);
    }
    const float mean = s * (1.f / 116.f);
    float var = s2 * (1.f / 116.f) - mean * mean;
    const float rstd = 1.f / sqrtf(var + 1e-5f);
#pragma unroll
    for (int jj = 0; jj < 8; ++jj) {
      const int j = tx + 16 * jj;
      if (j < 116)
        Y[(size_t)tok * 116 + j] = (v[jj] - mean) * rstd * g[j] + beta[j];
    }
  }
}

// ---------------------------------------------------------------------------
// Attention: one block = one (n,h) pair, 64 threads (one per query row s).
// qkv layout: [tok=s*512+n][348] with q|k|v at offsets 0|116|232, head h at h*29.
// ---------------------------------------------------------------------------
__global__ __launch_bounds__(64) void attn_kernel(const float* __restrict__ qkv,
                                                  float* __restrict__ obuf) {
  const int h = blockIdx.x & 3;
  const int n = blockIdx.x >> 2;
  const int s = threadIdx.x;
  __shared__ float ks[64][30];
  __shared__ float vs[64][30];

  const size_t base = ((size_t)s * 512 + n) * 348 + h * 29;
  float q[29];
#pragma unroll
  for (int d = 0; d < 29; ++d) {
    q[d] = qkv[base + d];
    ks[s][d] = qkv[base + 116 + d];
    vs[s][d] = qkv[base + 232 + d];
  }
  __syncthreads();

  const float scale = 0.18569533817705186f;  // 1/sqrt(29)
  float sc[64];
#pragma unroll
  for (int t = 0; t < 64; ++t) {
    float a = 0.f;
#pragma unroll
    for (int d = 0; d < 29; ++d) a = fmaf(q[d], ks[t][d], a);
    sc[t] = a * scale;
  }
  float m = sc[0];
#pragma unroll
  for (int t = 1; t < 64; ++t) m = fmaxf(m, sc[t]);
  float sum = 0.f;
#pragma unroll
  for (int t = 0; t < 64; ++t) {
    sc[t] = __expf(sc[t] - m);
    sum += sc[t];
  }
  const float inv = 1.f / sum;
  float o[29] = {};
#pragma unroll
  for (int t = 0; t < 64; ++t) {
    const float p = sc[t];
#pragma unroll
    for (int d = 0; d < 29; ++d) o[d] = fmaf(p, vs[t][d], o[d]);
  }
  const size_t ob = ((size_t)s * 512 + n) * 116 + h * 29;
#pragma unroll
  for (int d = 0; d < 29; ++d) obuf[ob + d] = o[d] * inv;
}

// ---------------------------------------------------------------------------
// fc: feas[b,h,e] = sum_t x4[b,t,e] * fc_w[h,t] + fc_b[h]
// grid (4 e-groups, 64 b), block 256: h=tid&63, jg=tid>>6, e=e0+jg+4m.
// ---------------------------------------------------------------------------
__global__ __launch_bounds__(256) void fc_kernel(const float* __restrict__ X4,
                                                 const float* __restrict__ fw,
                                                 const float* __restrict__ fb,
                                                 float* __restrict__ fea) {
  const int eg = blockIdx.x;  // 0..3
  const int b = blockIdx.y;   // 0..63
  const int e0 = eg * 29;
  __shared__ float Os[64][30];
  __shared__ float Wf[64][65];
  const int tid = threadIdx.x;
  const int h = tid & 63, jg = tid >> 6;
  float acc[8] = {};

  for (int tc = 0; tc < 8; ++tc) {
    for (int idx = tid; idx < 64 * 29; idx += 256) {
      int tt = idx / 29;
      int ee = idx - tt * 29;
      Os[tt][ee] = X4[((size_t)b * 512 + tc * 64 + tt) * 116 + e0 + ee];
    }
    for (int idx = tid; idx < 64 * 64; idx += 256) {
      int hh = idx >> 6, t2 = idx & 63;
      Wf[hh][t2] = fw[(size_t)hh * 512 + tc * 64 + t2];
    }
    __syncthreads();
#pragma unroll 4
    for (int t = 0; t < 64; ++t) {
      const float w = Wf[h][t];
#pragma unroll
      for (int m = 0; m < 8; ++m) {
        const int el = jg + 4 * m;
        if (el < 29) acc[m] = fmaf(Os[t][el], w, acc[m]);
      }
    }
    __syncthreads();
  }
  const float bb = fb[h];
#pragma unroll
  for (int m = 0; m < 8; ++m) {
    const int el = jg + 4 * m;
    if (el < 29) fea[((size_t)b * 64 + h) * 116 + e0 + el] = acc[m] + bb;
  }
}

// ---------------------------------------------------------------------------
// Similarity: one block per (b,a).  dot[d,c] = sum_h feas[b,h,d]*sim[a,h,c];
// similarity = dot / max(fn[d]*sn[c],1e-8); similar = similarity / row-norm.
// fn/sn recomputed in-block from the staged tiles (no extra global scratch).
// ---------------------------------------------------------------------------
__global__ __launch_bounds__(256) void sim_kernel(const float* __restrict__ fea,
                                                  const float* __restrict__ sim,
                                                  float* __restrict__ simil,
                                                  float* __restrict__ similar) {
  const int a = blockIdx.x;  // 0..115
  const int b = blockIdx.y;  // 0..63
  __shared__ float Fs[64][129];
  __shared__ float Ss[64][97];
  __shared__ float fnrow[116];
  __shared__ float snrow[90];
  __shared__ float wred[4];
  const int tid = threadIdx.x;

  for (int idx = tid; idx < 64 * 128; idx += 256) {
    int hh = idx >> 7, ee = idx & 127;
    Fs[hh][ee] = (ee < 116) ? fea[((size_t)b * 64 + hh) * 116 + ee] : 0.f;
  }
  for (int idx = tid; idx < 64 * 96; idx += 256) {
    int hh = idx / 96, cc = idx - hh * 96;
    Ss[hh][cc] = (cc < 90) ? sim[((size_t)a * 64 + hh) * 90 + cc] : 0.f;
  }
  __syncthreads();

  if (tid < 116) {
    float s = 0.f;
#pragma unroll 8
    for (int hh = 0; hh < 64; ++hh) {
      float t = Fs[hh][tid];
      s = fmaf(t, t, s);
    }
    fnrow[tid] = sqrtf(s);
  } else if (tid >= 128 && tid < 218) {
    const int c = tid - 128;
    float s = 0.f;
#pragma unroll 8
    for (int hh = 0; hh < 64; ++hh) {
      float t = Ss[hh][c];
      s = fmaf(t, t, s);
    }
    snrow[c] = sqrtf(s);
  }
  __syncthreads();

  const int tx = tid & 15, ty = tid >> 4;
  float acc[8][6] = {};
#pragma unroll 2
  for (int hh = 0; hh < 64; ++hh) {
    float fv[8], sv[6];
#pragma unroll
    for (int di = 0; di < 8; ++di) fv[di] = Fs[hh][ty + 16 * di];
#pragma unroll
    for (int ci = 0; ci < 6; ++ci) sv[ci] = Ss[hh][tx + 16 * ci];
#pragma unroll
    for (int di = 0; di < 8; ++di)
#pragma unroll
      for (int ci = 0; ci < 6; ++ci) acc[di][ci] = fmaf(fv[di], sv[ci], acc[di][ci]);
  }

  const size_t rowbase = ((size_t)b * 116 + a) * 116 * 90;
  float ss = 0.f;
#pragma unroll
  for (int di = 0; di < 8; ++di) {
    const int d = ty + 16 * di;
    if (d < 116) {
      const float fn = fnrow[d];
#pragma unroll
      for (int ci = 0; ci < 6; ++ci) {
        const int c = tx + 16 * ci;
        if (c < 90) {
          const float denom = fmaxf(fn * snrow[c], 1e-8f);
          const float v = acc[di][ci] / denom;
          acc[di][ci] = v;
          ss = fmaf(v, v, ss);
          simil[rowbase + (size_t)d * 90 + c] = v;
        }
      }
    }
  }
  // block reduction of ss
  for (int m = 1; m <= 32; m <<= 1) ss += __shfl_xor(ss, m, 64);
  if ((tid & 63) == 0) wred[tid >> 6] = ss;
  __syncthreads();
  const float tot = wred[0] + wred[1] + wred[2] + wred[3];
  const float inv = 1.f / fmaxf(sqrtf(tot), 1e-12f);
#pragma unroll
  for (int di = 0; di < 8; ++di) {
    const int d = ty + 16 * di;
    if (d < 116) {
#pragma unroll
      for (int ci = 0; ci < 6; ++ci) {
        const int c = tx + 16 * ci;
        if (c < 90) similar[rowbase + (size_t)d * 90 + c] = acc[di][ci] * inv;
      }
    }
  }
}

// ---------------------------------------------------------------------------
extern "C" void kernel_launch(void* const* d_in, const int* in_sizes, int n_in,
                              void* d_out, int out_size, void* d_ws,
                              size_t ws_size, hipStream_t stream) {
  const float* x0 = (const float*)d_in[0];
  const float* sim = (const float*)d_in[1];
  const float* p[24];
  for (int i = 0; i < 24; ++i) p[i] = (const float*)d_in[2 + i];
  const float* fc_w = (const float*)d_in[26];
  const float* fc_b = (const float*)d_in[27];

  float* out = (float*)d_out;
  // output regions (sizes: fea 64*64*116 = 475,136 ; similarity and similar
  // each 64*116*116*90 = 77,506,560 ; total 155,488,256 = out_size)
  float* fea = out;
  float* simil = out + 475136;
  float* similar = out + 77981696;  // 475136 + 77506560
  // scratch carved out of not-yet-written output regions:
  float* qkvbuf = similar;                 // 11,403,264 floats
  float* obuf = similar + 11403264;        // 3,801,088
  float* xb1 = similar + 15204352;
  float* xb2 = similar + 19005440;
  float* xb3 = similar + 22806528;
  float* xb4 = similar + 26607616;         // ends at +30,408,704 < 77,506,560
  float* hbuf = simil;                     // 67,108,864 < 77,506,560

  const float* xin = x0;
  float* xa_arr[2] = {xb1, xb3};
  float* xb_arr[2] = {xb2, xb4};

  for (int L = 0; L < 2; ++L) {
    const float* wqkv = p[L * 12 + 0];
    const float* bqkv = p[L * 12 + 1];
    const float* wo = p[L * 12 + 2];
    const float* bo = p[L * 12 + 3];
    const float* g1 = p[L * 12 + 4];
    const float* bn1 = p[L * 12 + 5];
    const float* w1 = p[L * 12 + 6];
    const float* b1 = p[L * 12 + 7];
    const float* w2 = p[L * 12 + 8];
    const float* b2 = p[L * 12 + 9];
    const float* g2 = p[L * 12 + 10];
    const float* bn2 = p[L * 12 + 11];
    float* xa = xa_arr[L];
    float* xb = xb_arr[L];

    hipLaunchKernelGGL(gemm_k116_kernel, dim3(512, 6), dim3(256), 0, stream,
                       xin, wqkv, bqkv, qkvbuf, 348, 0);
    hipLaunchKernelGGL(attn_kernel, dim3(2048), dim3(64), 0, stream, qkvbuf,
                       obuf);
    hipLaunchKernelGGL(gemm_res_ln_kernel, dim3(512), dim3(256), 0, stream,
                       obuf, wo, bo, xin, g1, bn1, xa, 116);
    hipLaunchKernelGGL(gemm_k116_kernel, dim3(512, 32), dim3(256), 0, stream,
                       xa, w1, b1, hbuf, 2048, 1);
    hipLaunchKernelGGL(gemm_res_ln_kernel, dim3(512), dim3(256), 0, stream,
                       hbuf, w2, b2, xa, g2, bn2, xb, 2048);
    xin = xb;
  }

  hipLaunchKernelGGL(fc_kernel, dim3(4, 64), dim3(256), 0, stream, xb4, fc_w,
                     fc_b, fea);
  hipLaunchKernelGGL(sim_kernel, dim3(116, 64), dim3(256), 0, stream, fea, sim,
                     simil, similar);
}

// Round 3
// 1028.692 us; speedup vs baseline: 3.8651x; 3.8651x over previous
//
#include <hip/hip_runtime.h>
#include <hip/hip_bf16.h>

typedef __attribute__((ext_vector_type(8))) short short8v;
typedef __attribute__((ext_vector_type(4))) float floatx4;

__device__ __forceinline__ float bf2f(unsigned short u) {
  union { unsigned int i; float f; } c;
  c.i = ((unsigned int)u) << 16;
  return c.f;
}
__device__ __forceinline__ unsigned short f2bf(float f) {
  __hip_bfloat16 h = __float2bfloat16(f);
  return *reinterpret_cast<unsigned short*>(&h);
}

// ---------------------------------------------------------------------------
// fp32 [R x K] -> bf16 [R x Kp], zero-padded cols K..Kp-1.
// ---------------------------------------------------------------------------
__global__ __launch_bounds__(256) void convert_pad_kernel(
    const float* __restrict__ src, unsigned short* __restrict__ dst, int R,
    int K, int Kp) {
  const int total = R * Kp;
  for (int idx = blockIdx.x * 256 + threadIdx.x; idx < total;
       idx += gridDim.x * 256) {
    const int r = idx / Kp, c = idx - r * Kp;
    dst[idx] = (c < K) ? f2bf(src[(size_t)r * K + c]) : (unsigned short)0;
  }
}

// ---------------------------------------------------------------------------
// MFMA GEMM: Y[M,N] = A[M,Kp](bf16) @ B[N,Kp](bf16)^T  (+ epilogues)
// MODE 0: +bias -> bf16 out (ld=ldout)
// MODE 1: +bias, relu -> bf16 out (ld=ldout)
// MODE 2: +bias +res(fp32 ld116), LayerNorm(g,b) -> fp32 out (ld116)
//         AND bf16 out (ld128, cols 116..127 zeroed).  Requires N=116, grid.y=1.
// 128x128 tile, 256 thr = 4 waves (2x2), per-wave 4x4 frags of 16x16x32.
// LDS: A/B k-chunks of 64, XOR-swizzled 16B chunks (chunk ^= row&7).
// ---------------------------------------------------------------------------
template <int MODE>
__global__ __launch_bounds__(256) void mgemm_kernel(
    const unsigned short* __restrict__ A, const unsigned short* __restrict__ B,
    const float* __restrict__ bias, int N, int Kp, int ldout,
    unsigned short* __restrict__ Yb, float* __restrict__ Yf,
    const float* __restrict__ res, const float* __restrict__ gw,
    const float* __restrict__ bw) {
  __shared__ __align__(16) unsigned short As[128][64];
  __shared__ __align__(16) unsigned short Bs[128][64];
  __shared__ float sum1[2][128];
  __shared__ float sum2[2][128];

  const int tid = threadIdx.x;
  const int M0 = blockIdx.x * 128;
  const int N0 = blockIdx.y * 128;
  const int wid = tid >> 6, lane = tid & 63;
  const int wr = wid >> 1, wc = wid & 1;
  const int lc = lane & 15, g = lane >> 4;
  const int srow = tid >> 1, shalf = tid & 1;
  const int sw = srow & 7;

  floatx4 acc[4][4] = {};

  const int nk = Kp >> 6;
  for (int kt = 0; kt < nk; ++kt) {
    const int k0 = kt << 6;
    // ---- stage A (no row guard: M covered) ----
    {
      const uint4* p = reinterpret_cast<const uint4*>(
          A + (size_t)(M0 + srow) * Kp + k0 + shalf * 32);
      uint4 v0 = p[0], v1 = p[1], v2 = p[2], v3 = p[3];
      *reinterpret_cast<uint4*>(&As[srow][((((shalf << 2) | 0) ^ sw) << 3)]) = v0;
      *reinterpret_cast<uint4*>(&As[srow][((((shalf << 2) | 1) ^ sw) << 3)]) = v1;
      *reinterpret_cast<uint4*>(&As[srow][((((shalf << 2) | 2) ^ sw) << 3)]) = v2;
      *reinterpret_cast<uint4*>(&As[srow][((((shalf << 2) | 3) ^ sw) << 3)]) = v3;
    }
    // ---- stage B (row-guarded) ----
    {
      uint4 v0 = {0, 0, 0, 0}, v1 = v0, v2 = v0, v3 = v0;
      const int jr = N0 + srow;
      if (jr < N) {
        const uint4* p = reinterpret_cast<const uint4*>(
            B + (size_t)jr * Kp + k0 + shalf * 32);
        v0 = p[0]; v1 = p[1]; v2 = p[2]; v3 = p[3];
      }
      *reinterpret_cast<uint4*>(&Bs[srow][((((shalf << 2) | 0) ^ sw) << 3)]) = v0;
      *reinterpret_cast<uint4*>(&Bs[srow][((((shalf << 2) | 1) ^ sw) << 3)]) = v1;
      *reinterpret_cast<uint4*>(&Bs[srow][((((shalf << 2) | 2) ^ sw) << 3)]) = v2;
      *reinterpret_cast<uint4*>(&Bs[srow][((((shalf << 2) | 3) ^ sw) << 3)]) = v3;
    }
    __syncthreads();
    // ---- compute: 2 k-steps of 32, 16 MFMA each ----
#pragma unroll
    for (int ks = 0; ks < 2; ++ks) {
      short8v a[4], b[4];
#pragma unroll
      for (int m = 0; m < 4; ++m) {
        const int row = wr * 64 + m * 16 + lc;
        a[m] = *reinterpret_cast<const short8v*>(
            &As[row][((((ks << 2) | g) ^ (lc & 7)) << 3)]);
      }
#pragma unroll
      for (int n = 0; n < 4; ++n) {
        const int col = wc * 64 + n * 16 + lc;
        b[n] = *reinterpret_cast<const short8v*>(
            &Bs[col][((((ks << 2) | g) ^ (lc & 7)) << 3)]);
      }
#pragma unroll
      for (int m = 0; m < 4; ++m)
#pragma unroll
        for (int n = 0; n < 4; ++n)
          acc[m][n] = __builtin_amdgcn_mfma_f32_16x16x32_bf16(a[m], b[n],
                                                              acc[m][n], 0, 0, 0);
    }
    __syncthreads();
  }

  if constexpr (MODE != 2) {
#pragma unroll
    for (int m = 0; m < 4; ++m) {
#pragma unroll
      for (int r = 0; r < 4; ++r) {
        const int row = M0 + wr * 64 + m * 16 + g * 4 + r;
#pragma unroll
        for (int n = 0; n < 4; ++n) {
          const int col = N0 + wc * 64 + n * 16 + lc;
          if (col < N) {
            float v = acc[m][n][r] + bias[col];
            if (MODE == 1) v = fmaxf(v, 0.f);
            Yb[(size_t)row * ldout + col] = f2bf(v);
          }
        }
      }
    }
  } else {
    // fused residual + LayerNorm epilogue (N=116, cols 116..127 are zero pads)
    float s1l[4][4], s2l[4][4];
#pragma unroll
    for (int m = 0; m < 4; ++m) {
#pragma unroll
      for (int r = 0; r < 4; ++r) {
        const int row = M0 + wr * 64 + m * 16 + g * 4 + r;
        float s = 0.f, s2 = 0.f;
#pragma unroll
        for (int n = 0; n < 4; ++n) {
          const int col = wc * 64 + n * 16 + lc;
          float v = 0.f;
          if (col < 116)
            v = acc[m][n][r] + bias[col] + res[(size_t)row * 116 + col];
          acc[m][n][r] = v;
          s += v;
          s2 = fmaf(v, v, s2);
        }
#pragma unroll
        for (int st = 1; st < 16; st <<= 1) {
          s += __shfl_xor(s, st, 64);
          s2 += __shfl_xor(s2, st, 64);
        }
        s1l[m][r] = s;
        s2l[m][r] = s2;
      }
    }
    if (lc == 0) {
#pragma unroll
      for (int m = 0; m < 4; ++m)
#pragma unroll
        for (int r = 0; r < 4; ++r) {
          const int lrow = wr * 64 + m * 16 + g * 4 + r;
          sum1[wc][lrow] = s1l[m][r];
          sum2[wc][lrow] = s2l[m][r];
        }
    }
    __syncthreads();
#pragma unroll
    for (int m = 0; m < 4; ++m) {
#pragma unroll
      for (int r = 0; r < 4; ++r) {
        const int lrow = wr * 64 + m * 16 + g * 4 + r;
        const int row = M0 + lrow;
        const float st = sum1[0][lrow] + sum1[1][lrow];
        const float s2t = sum2[0][lrow] + sum2[1][lrow];
        const float mean = st * (1.f / 116.f);
        const float var = s2t * (1.f / 116.f) - mean * mean;
        const float rstd = 1.f / sqrtf(var + 1e-5f);
#pragma unroll
        for (int n = 0; n < 4; ++n) {
          const int col = wc * 64 + n * 16 + lc;
          if (col < 116) {
            const float y = (acc[m][n][r] - mean) * rstd * gw[col] + bw[col];
            Yf[(size_t)row * 116 + col] = y;
            Yb[(size_t)row * 128 + col] = f2bf(y);
          } else {
            Yb[(size_t)row * 128 + col] = 0;
          }
        }
      }
    }
  }
}

// ---------------------------------------------------------------------------
// Attention: one block = one (n,h), 64 threads (one per query row s).
// qkv bf16 [tok=s*512+n][348], q|k|v at 0|116|232, head at h*29.
// Writes obuf bf16 [tok][128] (h==3 zero-fills pad cols 116..127).
// ---------------------------------------------------------------------------
__global__ __launch_bounds__(64) void attn_kernel(
    const unsigned short* __restrict__ qkv, unsigned short* __restrict__ obuf) {
  const int h = blockIdx.x & 3;
  const int n = blockIdx.x >> 2;
  const int s = threadIdx.x;
  __shared__ float ks[64][30];
  __shared__ float vs[64][30];

  const size_t base = ((size_t)s * 512 + n) * 348 + h * 29;
  float q[29];
#pragma unroll
  for (int d = 0; d < 29; ++d) {
    q[d] = bf2f(qkv[base + d]);
    ks[s][d] = bf2f(qkv[base + 116 + d]);
    vs[s][d] = bf2f(qkv[base + 232 + d]);
  }
  __syncthreads();

  const float scale = 0.18569533817705186f;  // 1/sqrt(29)
  float sc[64];
#pragma unroll
  for (int t = 0; t < 64; ++t) {
    float a = 0.f;
#pragma unroll
    for (int d = 0; d < 29; ++d) a = fmaf(q[d], ks[t][d], a);
    sc[t] = a * scale;
  }
  float m = sc[0];
#pragma unroll
  for (int t = 1; t < 64; ++t) m = fmaxf(m, sc[t]);
  float sum = 0.f;
#pragma unroll
  for (int t = 0; t < 64; ++t) {
    sc[t] = __expf(sc[t] - m);
    sum += sc[t];
  }
  const float inv = 1.f / sum;
  float o[29] = {};
#pragma unroll
  for (int t = 0; t < 64; ++t) {
    const float p = sc[t];
#pragma unroll
    for (int d = 0; d < 29; ++d) o[d] = fmaf(p, vs[t][d], o[d]);
  }
  const size_t ob = ((size_t)s * 512 + n) * 128 + h * 29;
#pragma unroll
  for (int d = 0; d < 29; ++d) obuf[ob + d] = f2bf(o[d] * inv);
  if (h == 3) {
    const size_t pb = ((size_t)s * 512 + n) * 128;
#pragma unroll
    for (int c = 116; c < 128; ++c) obuf[pb + c] = 0;
  }
}

// ---------------------------------------------------------------------------
// fc: feas[b,h,e] = sum_t x4[b,t,e] * fc_w[h,t] + fc_b[h]   (fp32)
// ---------------------------------------------------------------------------
__global__ __launch_bounds__(256) void fc_kernel(const float* __restrict__ X4,
                                                 const float* __restrict__ fw,
                                                 const float* __restrict__ fb,
                                                 float* __restrict__ fea) {
  const int eg = blockIdx.x;  // 0..3
  const int b = blockIdx.y;   // 0..63
  const int e0 = eg * 29;
  __shared__ float Os[64][30];
  __shared__ float Wf[64][65];
  const int tid = threadIdx.x;
  const int h = tid & 63, jg = tid >> 6;
  float acc[8] = {};

  for (int tc = 0; tc < 8; ++tc) {
    for (int idx = tid; idx < 64 * 29; idx += 256) {
      int tt = idx / 29;
      int ee = idx - tt * 29;
      Os[tt][ee] = X4[((size_t)b * 512 + tc * 64 + tt) * 116 + e0 + ee];
    }
    for (int idx = tid; idx < 64 * 64; idx += 256) {
      int hh = idx >> 6, t2 = idx & 63;
      Wf[hh][t2] = fw[(size_t)hh * 512 + tc * 64 + t2];
    }
    __syncthreads();
#pragma unroll 4
    for (int t = 0; t < 64; ++t) {
      const float w = Wf[h][t];
#pragma unroll
      for (int m = 0; m < 8; ++m) {
        const int el = jg + 4 * m;
        if (el < 29) acc[m] = fmaf(Os[t][el], w, acc[m]);
      }
    }
    __syncthreads();
  }
  const float bb = fb[h];
#pragma unroll
  for (int m = 0; m < 8; ++m) {
    const int el = jg + 4 * m;
    if (el < 29) fea[((size_t)b * 64 + h) * 116 + e0 + el] = acc[m] + bb;
  }
}

// ---------------------------------------------------------------------------
// Similarity (fp32, unchanged from round 2)
// ---------------------------------------------------------------------------
__global__ __launch_bounds__(256) void sim_kernel(const float* __restrict__ fea,
                                                  const float* __restrict__ sim,
                                                  float* __restrict__ simil,
                                                  float* __restrict__ similar) {
  const int a = blockIdx.x;  // 0..115
  const int b = blockIdx.y;  // 0..63
  __shared__ float Fs[64][129];
  __shared__ float Ss[64][97];
  __shared__ float fnrow[116];
  __shared__ float snrow[90];
  __shared__ float wred[4];
  const int tid = threadIdx.x;

  for (int idx = tid; idx < 64 * 128; idx += 256) {
    int hh = idx >> 7, ee = idx & 127;
    Fs[hh][ee] = (ee < 116) ? fea[((size_t)b * 64 + hh) * 116 + ee] : 0.f;
  }
  for (int idx = tid; idx < 64 * 96; idx += 256) {
    int hh = idx / 96, cc = idx - hh * 96;
    Ss[hh][cc] = (cc < 90) ? sim[((size_t)a * 64 + hh) * 90 + cc] : 0.f;
  }
  __syncthreads();

  if (tid < 116) {
    float s = 0.f;
#pragma unroll 8
    for (int hh = 0; hh < 64; ++hh) {
      float t = Fs[hh][tid];
      s = fmaf(t, t, s);
    }
    fnrow[tid] = sqrtf(s);
  } else if (tid >= 128 && tid < 218) {
    const int c = tid - 128;
    float s = 0.f;
#pragma unroll 8
    for (int hh = 0; hh < 64; ++hh) {
      float t = Ss[hh][c];
      s = fmaf(t, t, s);
    }
    snrow[c] = sqrtf(s);
  }
  __syncthreads();

  const int tx = tid & 15, ty = tid >> 4;
  float acc[8][6] = {};
#pragma unroll 2
  for (int hh = 0; hh < 64; ++hh) {
    float fv[8], sv[6];
#pragma unroll
    for (int di = 0; di < 8; ++di) fv[di] = Fs[hh][ty + 16 * di];
#pragma unroll
    for (int ci = 0; ci < 6; ++ci) sv[ci] = Ss[hh][tx + 16 * ci];
#pragma unroll
    for (int di = 0; di < 8; ++di)
#pragma unroll
      for (int ci = 0; ci < 6; ++ci) acc[di][ci] = fmaf(fv[di], sv[ci], acc[di][ci]);
  }

  const size_t rowbase = ((size_t)b * 116 + a) * 116 * 90;
  float ss = 0.f;
#pragma unroll
  for (int di = 0; di < 8; ++di) {
    const int d = ty + 16 * di;
    if (d < 116) {
      const float fn = fnrow[d];
#pragma unroll
      for (int ci = 0; ci < 6; ++ci) {
        const int c = tx + 16 * ci;
        if (c < 90) {
          const float denom = fmaxf(fn * snrow[c], 1e-8f);
          const float v = acc[di][ci] / denom;
          acc[di][ci] = v;
          ss = fmaf(v, v, ss);
          simil[rowbase + (size_t)d * 90 + c] = v;
        }
      }
    }
  }
  for (int m = 1; m <= 32; m <<= 1) ss += __shfl_xor(ss, m, 64);
  if ((tid & 63) == 0) wred[tid >> 6] = ss;
  __syncthreads();
  const float tot = wred[0] + wred[1] + wred[2] + wred[3];
  const float inv = 1.f / fmaxf(sqrtf(tot), 1e-12f);
#pragma unroll
  for (int di = 0; di < 8; ++di) {
    const int d = ty + 16 * di;
    if (d < 116) {
#pragma unroll
      for (int ci = 0; ci < 6; ++ci) {
        const int c = tx + 16 * ci;
        if (c < 90) similar[rowbase + (size_t)d * 90 + c] = acc[di][ci] * inv;
      }
    }
  }
}

// ---------------------------------------------------------------------------
extern "C" void kernel_launch(void* const* d_in, const int* in_sizes, int n_in,
                              void* d_out, int out_size, void* d_ws,
                              size_t ws_size, hipStream_t stream) {
  const float* x0 = (const float*)d_in[0];
  const float* simin = (const float*)d_in[1];
  const float* p[24];
  for (int i = 0; i < 24; ++i) p[i] = (const float*)d_in[2 + i];
  const float* fc_w = (const float*)d_in[26];
  const float* fc_b = (const float*)d_in[27];

  float* out = (float*)d_out;
  float* fea = out;
  float* simil = out + 475136;       // 64*116*116*90 = 77,506,560 floats
  float* similar = out + 77981696;   // 475136 + 77506560

  // scratch in 'similar' region (dead before sim_kernel writes it):
  float* xa_f[2] = {similar + 0, similar + 7602176};
  float* xb_f[2] = {similar + 3801088, similar + 11403264};
  unsigned short* Ab = (unsigned short*)(similar + 15204352);     // 32768x128
  unsigned short* obufb = (unsigned short*)(similar + 17301504);  // 32768x128
  unsigned short* xab[2] = {(unsigned short*)(similar + 19398656),
                            (unsigned short*)(similar + 23592960)};
  unsigned short* xbb[2] = {(unsigned short*)(similar + 21495808),
                            (unsigned short*)(similar + 25690112)};
  unsigned short* qkvb = (unsigned short*)(similar + 27787264);   // 32768x348
  // scratch in 'simil' region:
  unsigned short* hbufb = (unsigned short*)simil;                 // 32768x2048
  unsigned short* wbuf = (unsigned short*)(simil + 33554432);
  // per-layer weight offsets (ushort units): wqkv 44544, wo 14848, w1 262144, w2 237568
  const size_t WSZ = 44544 + 14848 + 262144 + 237568;  // 559104

  auto conv = [&](const float* s, unsigned short* dd, int R, int K, int Kp) {
    int total = R * Kp;
    int blocks = (total + 255) / 256;
    if (blocks > 2048) blocks = 2048;
    hipLaunchKernelGGL(convert_pad_kernel, dim3(blocks), dim3(256), 0, stream,
                       s, dd, R, K, Kp);
  };

  conv(x0, Ab, 32768, 116, 128);
  for (int L = 0; L < 2; ++L) {
    unsigned short* wb = wbuf + L * WSZ;
    conv(p[L * 12 + 0], wb + 0, 348, 116, 128);              // wqkv
    conv(p[L * 12 + 2], wb + 44544, 116, 116, 128);          // wo
    conv(p[L * 12 + 6], wb + 59392, 2048, 116, 128);         // w1
    conv(p[L * 12 + 8], wb + 321536, 116, 2048, 2048);       // w2
  }

  const unsigned short* Ain = Ab;
  const float* resin = x0;
  for (int L = 0; L < 2; ++L) {
    unsigned short* wb = wbuf + L * WSZ;
    const float* bqkv = p[L * 12 + 1];
    const float* bo = p[L * 12 + 3];
    const float* g1 = p[L * 12 + 4];
    const float* bn1 = p[L * 12 + 5];
    const float* b1 = p[L * 12 + 7];
    const float* b2 = p[L * 12 + 9];
    const float* g2 = p[L * 12 + 10];
    const float* bn2 = p[L * 12 + 11];

    // qkv = Ain @ wqkv^T + bqkv  -> bf16 [32768 x 348]
    hipLaunchKernelGGL((mgemm_kernel<0>), dim3(256, 3), dim3(256), 0, stream,
                       Ain, wb + 0, bqkv, 348, 128, 348, qkvb, (float*)nullptr,
                       (const float*)nullptr, (const float*)nullptr,
                       (const float*)nullptr);
    hipLaunchKernelGGL(attn_kernel, dim3(2048), dim3(64), 0, stream, qkvb,
                       obufb);
    // o-proj + res + LN -> xa (f32 + bf16)
    hipLaunchKernelGGL((mgemm_kernel<2>), dim3(256, 1), dim3(256), 0, stream,
                       obufb, wb + 44544, bo, 116, 128, 0, xab[L], xa_f[L],
                       resin, g1, bn1);
    // FFN1: relu(xa @ w1^T + b1) -> bf16 [32768 x 2048]
    hipLaunchKernelGGL((mgemm_kernel<1>), dim3(256, 16), dim3(256), 0, stream,
                       xab[L], wb + 59392, b1, 2048, 128, 2048, hbufb,
                       (float*)nullptr, (const float*)nullptr,
                       (const float*)nullptr, (const float*)nullptr);
    // FFN2 + res + LN -> xb (f32 + bf16)
    hipLaunchKernelGGL((mgemm_kernel<2>), dim3(256, 1), dim3(256), 0, stream,
                       hbufb, wb + 321536, b2, 116, 2048, 0, xbb[L], xb_f[L],
                       xa_f[L], g2, bn2);
    Ain = xbb[L];
    resin = xb_f[L];
  }

  hipLaunchKernelGGL(fc_kernel, dim3(4, 64), dim3(256), 0, stream, xb_f[1],
                     fc_w, fc_b, fea);
  hipLaunchKernelGGL(sim_kernel, dim3(116, 64), dim3(256), 0, stream, fea,
                     simin, simil, similar);
}

// Round 4
// 824.583 us; speedup vs baseline: 4.8218x; 1.2475x over previous
//
#include <hip/hip_runtime.h>
#include <hip/hip_bf16.h>

typedef __attribute__((ext_vector_type(8))) short short8v;
typedef __attribute__((ext_vector_type(4))) float floatx4;

__device__ __forceinline__ float bf2f(unsigned short u) {
  union { unsigned int i; float f; } c;
  c.i = ((unsigned int)u) << 16;
  return c.f;
}
__device__ __forceinline__ unsigned short f2bf(float f) {
  __hip_bfloat16 h = __float2bfloat16(f);
  return *reinterpret_cast<unsigned short*>(&h);
}

// ---------------------------------------------------------------------------
// fp32 [R x K] -> bf16 [R x Kp], zero-padded cols K..Kp-1.
// ---------------------------------------------------------------------------
__global__ __launch_bounds__(256) void convert_pad_kernel(
    const float* __restrict__ src, unsigned short* __restrict__ dst, int R,
    int K, int Kp) {
  const int total = R * Kp;
  for (int idx = blockIdx.x * 256 + threadIdx.x; idx < total;
       idx += gridDim.x * 256) {
    const int r = idx / Kp, c = idx - r * Kp;
    dst[idx] = (c < K) ? f2bf(src[(size_t)r * K + c]) : (unsigned short)0;
  }
}

// ---------------------------------------------------------------------------
// MFMA GEMM: Y[M,N] = A[M,Kp](bf16) @ B[N,Kp](bf16)^T  (+ epilogues)
// MODE 0: +bias -> bf16 out (ld=ldout)
// MODE 1: +bias, relu -> bf16 out (ld=ldout)
// MODE 2: +bias +res(fp32 ld116), LayerNorm(g,b) -> fp32 out (ld116)
//         AND bf16 out (ld128, cols 116..127 zeroed).  Requires N=116, grid.y=1.
// 128x128 tile, 256 thr = 4 waves (2x2), per-wave 4x4 frags of 16x16x32.
// LDS: A/B k-chunks of 64, XOR-swizzled 16B chunks (chunk ^= row&7).
// ---------------------------------------------------------------------------
template <int MODE>
__global__ __launch_bounds__(256) void mgemm_kernel(
    const unsigned short* __restrict__ A, const unsigned short* __restrict__ B,
    const float* __restrict__ bias, int N, int Kp, int ldout,
    unsigned short* __restrict__ Yb, float* __restrict__ Yf,
    const float* __restrict__ res, const float* __restrict__ gw,
    const float* __restrict__ bw) {
  __shared__ __align__(16) unsigned short As[128][64];
  __shared__ __align__(16) unsigned short Bs[128][64];
  __shared__ float sum1[2][128];
  __shared__ float sum2[2][128];

  const int tid = threadIdx.x;
  const int M0 = blockIdx.x * 128;
  const int N0 = blockIdx.y * 128;
  const int wid = tid >> 6, lane = tid & 63;
  const int wr = wid >> 1, wc = wid & 1;
  const int lc = lane & 15, g = lane >> 4;
  const int srow = tid >> 1, shalf = tid & 1;
  const int sw = srow & 7;

  floatx4 acc[4][4] = {};

  const int nk = Kp >> 6;
  for (int kt = 0; kt < nk; ++kt) {
    const int k0 = kt << 6;
    // ---- stage A (no row guard: M covered) ----
    {
      const uint4* p = reinterpret_cast<const uint4*>(
          A + (size_t)(M0 + srow) * Kp + k0 + shalf * 32);
      uint4 v0 = p[0], v1 = p[1], v2 = p[2], v3 = p[3];
      *reinterpret_cast<uint4*>(&As[srow][((((shalf << 2) | 0) ^ sw) << 3)]) = v0;
      *reinterpret_cast<uint4*>(&As[srow][((((shalf << 2) | 1) ^ sw) << 3)]) = v1;
      *reinterpret_cast<uint4*>(&As[srow][((((shalf << 2) | 2) ^ sw) << 3)]) = v2;
      *reinterpret_cast<uint4*>(&As[srow][((((shalf << 2) | 3) ^ sw) << 3)]) = v3;
    }
    // ---- stage B (row-guarded) ----
    {
      uint4 v0 = {0, 0, 0, 0}, v1 = v0, v2 = v0, v3 = v0;
      const int jr = N0 + srow;
      if (jr < N) {
        const uint4* p = reinterpret_cast<const uint4*>(
            B + (size_t)jr * Kp + k0 + shalf * 32);
        v0 = p[0]; v1 = p[1]; v2 = p[2]; v3 = p[3];
      }
      *reinterpret_cast<uint4*>(&Bs[srow][((((shalf << 2) | 0) ^ sw) << 3)]) = v0;
      *reinterpret_cast<uint4*>(&Bs[srow][((((shalf << 2) | 1) ^ sw) << 3)]) = v1;
      *reinterpret_cast<uint4*>(&Bs[srow][((((shalf << 2) | 2) ^ sw) << 3)]) = v2;
      *reinterpret_cast<uint4*>(&Bs[srow][((((shalf << 2) | 3) ^ sw) << 3)]) = v3;
    }
    __syncthreads();
    // ---- compute: 2 k-steps of 32, 16 MFMA each ----
#pragma unroll
    for (int ks = 0; ks < 2; ++ks) {
      short8v a[4], b[4];
#pragma unroll
      for (int m = 0; m < 4; ++m) {
        const int row = wr * 64 + m * 16 + lc;
        a[m] = *reinterpret_cast<const short8v*>(
            &As[row][((((ks << 2) | g) ^ (lc & 7)) << 3)]);
      }
#pragma unroll
      for (int n = 0; n < 4; ++n) {
        const int col = wc * 64 + n * 16 + lc;
        b[n] = *reinterpret_cast<const short8v*>(
            &Bs[col][((((ks << 2) | g) ^ (lc & 7)) << 3)]);
      }
#pragma unroll
      for (int m = 0; m < 4; ++m)
#pragma unroll
        for (int n = 0; n < 4; ++n)
          acc[m][n] = __builtin_amdgcn_mfma_f32_16x16x32_bf16(a[m], b[n],
                                                              acc[m][n], 0, 0, 0);
    }
    __syncthreads();
  }

  if constexpr (MODE != 2) {
#pragma unroll
    for (int m = 0; m < 4; ++m) {
#pragma unroll
      for (int r = 0; r < 4; ++r) {
        const int row = M0 + wr * 64 + m * 16 + g * 4 + r;
#pragma unroll
        for (int n = 0; n < 4; ++n) {
          const int col = N0 + wc * 64 + n * 16 + lc;
          if (col < N) {
            float v = acc[m][n][r] + bias[col];
            if (MODE == 1) v = fmaxf(v, 0.f);
            Yb[(size_t)row * ldout + col] = f2bf(v);
          }
        }
      }
    }
  } else {
    // fused residual + LayerNorm epilogue (N=116, cols 116..127 are zero pads)
    float s1l[4][4], s2l[4][4];
#pragma unroll
    for (int m = 0; m < 4; ++m) {
#pragma unroll
      for (int r = 0; r < 4; ++r) {
        const int row = M0 + wr * 64 + m * 16 + g * 4 + r;
        float s = 0.f, s2 = 0.f;
#pragma unroll
        for (int n = 0; n < 4; ++n) {
          const int col = wc * 64 + n * 16 + lc;
          float v = 0.f;
          if (col < 116)
            v = acc[m][n][r] + bias[col] + res[(size_t)row * 116 + col];
          acc[m][n][r] = v;
          s += v;
          s2 = fmaf(v, v, s2);
        }
#pragma unroll
        for (int st = 1; st < 16; st <<= 1) {
          s += __shfl_xor(s, st, 64);
          s2 += __shfl_xor(s2, st, 64);
        }
        s1l[m][r] = s;
        s2l[m][r] = s2;
      }
    }
    if (lc == 0) {
#pragma unroll
      for (int m = 0; m < 4; ++m)
#pragma unroll
        for (int r = 0; r < 4; ++r) {
          const int lrow = wr * 64 + m * 16 + g * 4 + r;
          sum1[wc][lrow] = s1l[m][r];
          sum2[wc][lrow] = s2l[m][r];
        }
    }
    __syncthreads();
#pragma unroll
    for (int m = 0; m < 4; ++m) {
#pragma unroll
      for (int r = 0; r < 4; ++r) {
        const int lrow = wr * 64 + m * 16 + g * 4 + r;
        const int row = M0 + lrow;
        const float st = sum1[0][lrow] + sum1[1][lrow];
        const float s2t = sum2[0][lrow] + sum2[1][lrow];
        const float mean = st * (1.f / 116.f);
        const float var = s2t * (1.f / 116.f) - mean * mean;
        const float rstd = 1.f / sqrtf(var + 1e-5f);
#pragma unroll
        for (int n = 0; n < 4; ++n) {
          const int col = wc * 64 + n * 16 + lc;
          if (col < 116) {
            const float y = (acc[m][n][r] - mean) * rstd * gw[col] + bw[col];
            Yf[(size_t)row * 116 + col] = y;
            Yb[(size_t)row * 128 + col] = f2bf(y);
          } else {
            Yb[(size_t)row * 128 + col] = 0;
          }
        }
      }
    }
  }
}

// ---------------------------------------------------------------------------
// Attention: one block = one (n,h), 64 threads (one per query row s).
// qkv bf16 [tok=s*512+n][348], q|k|v at 0|116|232, head at h*29.
// Writes obuf bf16 [tok][128] (h==3 zero-fills pad cols 116..127).
// ---------------------------------------------------------------------------
__global__ __launch_bounds__(64) void attn_kernel(
    const unsigned short* __restrict__ qkv, unsigned short* __restrict__ obuf) {
  const int h = blockIdx.x & 3;
  const int n = blockIdx.x >> 2;
  const int s = threadIdx.x;
  __shared__ float ks[64][30];
  __shared__ float vs[64][30];

  const size_t base = ((size_t)s * 512 + n) * 348 + h * 29;
  float q[29];
#pragma unroll
  for (int d = 0; d < 29; ++d) {
    q[d] = bf2f(qkv[base + d]);
    ks[s][d] = bf2f(qkv[base + 116 + d]);
    vs[s][d] = bf2f(qkv[base + 232 + d]);
  }
  __syncthreads();

  const float scale = 0.18569533817705186f;  // 1/sqrt(29)
  float sc[64];
#pragma unroll
  for (int t = 0; t < 64; ++t) {
    float a = 0.f;
#pragma unroll
    for (int d = 0; d < 29; ++d) a = fmaf(q[d], ks[t][d], a);
    sc[t] = a * scale;
  }
  float m = sc[0];
#pragma unroll
  for (int t = 1; t < 64; ++t) m = fmaxf(m, sc[t]);
  float sum = 0.f;
#pragma unroll
  for (int t = 0; t < 64; ++t) {
    sc[t] = __expf(sc[t] - m);
    sum += sc[t];
  }
  const float inv = 1.f / sum;
  float o[29] = {};
#pragma unroll
  for (int t = 0; t < 64; ++t) {
    const float p = sc[t];
#pragma unroll
    for (int d = 0; d < 29; ++d) o[d] = fmaf(p, vs[t][d], o[d]);
  }
  const size_t ob = ((size_t)s * 512 + n) * 128 + h * 29;
#pragma unroll
  for (int d = 0; d < 29; ++d) obuf[ob + d] = f2bf(o[d] * inv);
  if (h == 3) {
    const size_t pb = ((size_t)s * 512 + n) * 128;
#pragma unroll
    for (int c = 116; c < 128; ++c) obuf[pb + c] = 0;
  }
}

// ---------------------------------------------------------------------------
// fc: feas[b,h,e] = sum_t x4[b,t,e] * fc_w[h,t] + fc_b[h]   (fp32)
// ---------------------------------------------------------------------------
__global__ __launch_bounds__(256) void fc_kernel(const float* __restrict__ X4,
                                                 const float* __restrict__ fw,
                                                 const float* __restrict__ fb,
                                                 float* __restrict__ fea) {
  const int eg = blockIdx.x;  // 0..3
  const int b = blockIdx.y;   // 0..63
  const int e0 = eg * 29;
  __shared__ float Os[64][30];
  __shared__ float Wf[64][65];
  const int tid = threadIdx.x;
  const int h = tid & 63, jg = tid >> 6;
  float acc[8] = {};

  for (int tc = 0; tc < 8; ++tc) {
    for (int idx = tid; idx < 64 * 29; idx += 256) {
      int tt = idx / 29;
      int ee = idx - tt * 29;
      Os[tt][ee] = X4[((size_t)b * 512 + tc * 64 + tt) * 116 + e0 + ee];
    }
    for (int idx = tid; idx < 64 * 64; idx += 256) {
      int hh = idx >> 6, t2 = idx & 63;
      Wf[hh][t2] = fw[(size_t)hh * 512 + tc * 64 + t2];
    }
    __syncthreads();
#pragma unroll 4
    for (int t = 0; t < 64; ++t) {
      const float w = Wf[h][t];
#pragma unroll
      for (int m = 0; m < 8; ++m) {
        const int el = jg + 4 * m;
        if (el < 29) acc[m] = fmaf(Os[t][el], w, acc[m]);
      }
    }
    __syncthreads();
  }
  const float bb = fb[h];
#pragma unroll
  for (int m = 0; m < 8; ++m) {
    const int el = jg + 4 * m;
    if (el < 29) fea[((size_t)b * 64 + h) * 116 + e0 + el] = acc[m] + bb;
  }
}

// ---------------------------------------------------------------------------
// Similarity via MFMA.  Block per (b,a):
//   Ft[128][64] bf16 = fea[b][h][d] transposed (d-major), XOR-swizzled
//   St[96][64]  bf16 = sim[a][h][c] transposed (c-major), XOR-swizzled
//   dot[d,c] via mfma_f32_16x16x32_bf16 (4 waves 2x2, 4x3 frags, K=64)
//   fn/sn in-block fp32; epilogue: simil = dot/denoms, similar = simil/rownorm
// ---------------------------------------------------------------------------
__global__ __launch_bounds__(256) void sim_mfma_kernel(
    const float* __restrict__ fea, const float* __restrict__ simin,
    float* __restrict__ simil, float* __restrict__ similar) {
  const int a = blockIdx.x;  // 0..115
  const int b = blockIdx.y;  // 0..63
  __shared__ __align__(16) unsigned short Ft[128][64];
  __shared__ __align__(16) unsigned short St[96][64];
  __shared__ float fnrow[116];
  __shared__ float snrow[90];
  __shared__ float wred[4];
  const int tid = threadIdx.x;

  // stage + transpose + bf16-convert (coalesced global reads)
  for (int idx = tid; idx < 64 * 116; idx += 256) {
    const int h = idx / 116, d = idx - h * 116;
    Ft[d][(((h >> 3) ^ (d & 7)) << 3) | (h & 7)] =
        f2bf(fea[((size_t)b * 64 + h) * 116 + d]);
  }
  for (int idx = tid; idx < 12 * 64; idx += 256) {
    const int d = 116 + (idx >> 6), h = idx & 63;
    Ft[d][(((h >> 3) ^ (d & 7)) << 3) | (h & 7)] = 0;
  }
  for (int idx = tid; idx < 64 * 90; idx += 256) {
    const int h = idx / 90, c = idx - h * 90;
    St[c][(((h >> 3) ^ (c & 7)) << 3) | (h & 7)] =
        f2bf(simin[((size_t)a * 64 + h) * 90 + c]);
  }
  for (int idx = tid; idx < 6 * 64; idx += 256) {
    const int c = 90 + (idx >> 6), h = idx & 63;
    St[c][(((h >> 3) ^ (c & 7)) << 3) | (h & 7)] = 0;
  }
  __syncthreads();

  // column norms from the staged bf16 tiles (matches dot operands)
  if (tid < 116) {
    const int d = tid;
    float s = 0.f;
#pragma unroll 8
    for (int h = 0; h < 64; ++h) {
      const float t = bf2f(Ft[d][(((h >> 3) ^ (d & 7)) << 3) | (h & 7)]);
      s = fmaf(t, t, s);
    }
    fnrow[d] = sqrtf(s);
  } else if (tid >= 128 && tid < 218) {
    const int c = tid - 128;
    float s = 0.f;
#pragma unroll 8
    for (int h = 0; h < 64; ++h) {
      const float t = bf2f(St[c][(((h >> 3) ^ (c & 7)) << 3) | (h & 7)]);
      s = fmaf(t, t, s);
    }
    snrow[c] = sqrtf(s);
  }
  __syncthreads();

  const int wid = tid >> 6, lane = tid & 63;
  const int wr = wid >> 1, wc = wid & 1;   // wave tile: rows wr*64, cols wc*48
  const int lc = lane & 15, g = lane >> 4;

  floatx4 acc[4][3] = {};
#pragma unroll
  for (int ks = 0; ks < 2; ++ks) {
    short8v av[4], bv[3];
#pragma unroll
    for (int m = 0; m < 4; ++m) {
      const int row = wr * 64 + m * 16 + lc;
      av[m] = *reinterpret_cast<const short8v*>(
          &Ft[row][((((ks << 2) | g) ^ (lc & 7)) << 3)]);
    }
#pragma unroll
    for (int n = 0; n < 3; ++n) {
      const int col = wc * 48 + n * 16 + lc;
      bv[n] = *reinterpret_cast<const short8v*>(
          &St[col][((((ks << 2) | g) ^ (lc & 7)) << 3)]);
    }
#pragma unroll
    for (int m = 0; m < 4; ++m)
#pragma unroll
      for (int n = 0; n < 3; ++n)
        acc[m][n] = __builtin_amdgcn_mfma_f32_16x16x32_bf16(av[m], bv[n],
                                                            acc[m][n], 0, 0, 0);
  }

  // epilogue pass 1: similarity = dot/denom, accumulate row sum-of-squares
  const size_t rowbase = ((size_t)b * 116 + a) * (116 * 90);
  float ss = 0.f;
#pragma unroll
  for (int m = 0; m < 4; ++m) {
#pragma unroll
    for (int r = 0; r < 4; ++r) {
      const int d = wr * 64 + m * 16 + g * 4 + r;
      if (d < 116) {
        const float fn = fnrow[d];
#pragma unroll
        for (int n = 0; n < 3; ++n) {
          const int c = wc * 48 + n * 16 + lc;
          if (c < 90) {
            const float denom = fmaxf(fn * snrow[c], 1e-8f);
            float rcp = __builtin_amdgcn_rcpf(denom);
            rcp = rcp * (2.0f - denom * rcp);  // 1 Newton step
            const float v = acc[m][n][r] * rcp;
            acc[m][n][r] = v;
            ss = fmaf(v, v, ss);
            simil[rowbase + (size_t)d * 90 + c] = v;
          }
        }
      }
    }
  }
  // block reduction of ss
#pragma unroll
  for (int st = 1; st <= 32; st <<= 1) ss += __shfl_xor(ss, st, 64);
  if (lane == 0) wred[wid] = ss;
  __syncthreads();
  const float tot = wred[0] + wred[1] + wred[2] + wred[3];
  const float inv = 1.f / fmaxf(sqrtf(tot), 1e-12f);
  // epilogue pass 2: similar = similarity * inv
#pragma unroll
  for (int m = 0; m < 4; ++m) {
#pragma unroll
    for (int r = 0; r < 4; ++r) {
      const int d = wr * 64 + m * 16 + g * 4 + r;
      if (d < 116) {
#pragma unroll
        for (int n = 0; n < 3; ++n) {
          const int c = wc * 48 + n * 16 + lc;
          if (c < 90) similar[rowbase + (size_t)d * 90 + c] = acc[m][n][r] * inv;
        }
      }
    }
  }
}

// ---------------------------------------------------------------------------
extern "C" void kernel_launch(void* const* d_in, const int* in_sizes, int n_in,
                              void* d_out, int out_size, void* d_ws,
                              size_t ws_size, hipStream_t stream) {
  const float* x0 = (const float*)d_in[0];
  const float* simin = (const float*)d_in[1];
  const float* p[24];
  for (int i = 0; i < 24; ++i) p[i] = (const float*)d_in[2 + i];
  const float* fc_w = (const float*)d_in[26];
  const float* fc_b = (const float*)d_in[27];

  float* out = (float*)d_out;
  float* fea = out;
  float* simil = out + 475136;       // 64*116*116*90 = 77,506,560 floats
  float* similar = out + 77981696;   // 475136 + 77506560

  // scratch in 'similar' region (dead before sim_mfma_kernel writes it):
  float* xa_f[2] = {similar + 0, similar + 7602176};
  float* xb_f[2] = {similar + 3801088, similar + 11403264};
  unsigned short* Ab = (unsigned short*)(similar + 15204352);     // 32768x128
  unsigned short* obufb = (unsigned short*)(similar + 17301504);  // 32768x128
  unsigned short* xab[2] = {(unsigned short*)(similar + 19398656),
                            (unsigned short*)(similar + 23592960)};
  unsigned short* xbb[2] = {(unsigned short*)(similar + 21495808),
                            (unsigned short*)(similar + 25690112)};
  unsigned short* qkvb = (unsigned short*)(similar + 27787264);   // 32768x348
  // scratch in 'simil' region:
  unsigned short* hbufb = (unsigned short*)simil;                 // 32768x2048
  unsigned short* wbuf = (unsigned short*)(simil + 33554432);
  // per-layer weight offsets (ushort units): wqkv 44544, wo 14848, w1 262144, w2 237568
  const size_t WSZ = 44544 + 14848 + 262144 + 237568;  // 559104

  auto conv = [&](const float* s, unsigned short* dd, int R, int K, int Kp) {
    int total = R * Kp;
    int blocks = (total + 255) / 256;
    if (blocks > 2048) blocks = 2048;
    hipLaunchKernelGGL(convert_pad_kernel, dim3(blocks), dim3(256), 0, stream,
                       s, dd, R, K, Kp);
  };

  conv(x0, Ab, 32768, 116, 128);
  for (int L = 0; L < 2; ++L) {
    unsigned short* wb = wbuf + L * WSZ;
    conv(p[L * 12 + 0], wb + 0, 348, 116, 128);              // wqkv
    conv(p[L * 12 + 2], wb + 44544, 116, 116, 128);          // wo
    conv(p[L * 12 + 6], wb + 59392, 2048, 116, 128);         // w1
    conv(p[L * 12 + 8], wb + 321536, 116, 2048, 2048);       // w2
  }

  const unsigned short* Ain = Ab;
  const float* resin = x0;
  for (int L = 0; L < 2; ++L) {
    unsigned short* wb = wbuf + L * WSZ;
    const float* bqkv = p[L * 12 + 1];
    const float* bo = p[L * 12 + 3];
    const float* g1 = p[L * 12 + 4];
    const float* bn1 = p[L * 12 + 5];
    const float* b1 = p[L * 12 + 7];
    const float* b2 = p[L * 12 + 9];
    const float* g2 = p[L * 12 + 10];
    const float* bn2 = p[L * 12 + 11];

    // qkv = Ain @ wqkv^T + bqkv  -> bf16 [32768 x 348]
    hipLaunchKernelGGL((mgemm_kernel<0>), dim3(256, 3), dim3(256), 0, stream,
                       Ain, wb + 0, bqkv, 348, 128, 348, qkvb, (float*)nullptr,
                       (const float*)nullptr, (const float*)nullptr,
                       (const float*)nullptr);
    hipLaunchKernelGGL(attn_kernel, dim3(2048), dim3(64), 0, stream, qkvb,
                       obufb);
    // o-proj + res + LN -> xa (f32 + bf16)
    hipLaunchKernelGGL((mgemm_kernel<2>), dim3(256, 1), dim3(256), 0, stream,
                       obufb, wb + 44544, bo, 116, 128, 0, xab[L], xa_f[L],
                       resin, g1, bn1);
    // FFN1: relu(xa @ w1^T + b1) -> bf16 [32768 x 2048]
    hipLaunchKernelGGL((mgemm_kernel<1>), dim3(256, 16), dim3(256), 0, stream,
                       xab[L], wb + 59392, b1, 2048, 128, 2048, hbufb,
                       (float*)nullptr, (const float*)nullptr,
                       (const float*)nullptr, (const float*)nullptr);
    // FFN2 + res + LN -> xb (f32 + bf16)
    hipLaunchKernelGGL((mgemm_kernel<2>), dim3(256, 1), dim3(256), 0, stream,
                       hbufb, wb + 321536, b2, 116, 2048, 0, xbb[L], xb_f[L],
                       xa_f[L], g2, bn2);
    Ain = xbb[L];
    resin = xb_f[L];
  }

  hipLaunchKernelGGL(fc_kernel, dim3(4, 64), dim3(256), 0, stream, xb_f[1],
                     fc_w, fc_b, fea);
  hipLaunchKernelGGL(sim_mfma_kernel, dim3(116, 64), dim3(256), 0, stream, fea,
                     simin, simil, similar);
}

// Round 5
// 786.852 us; speedup vs baseline: 5.0530x; 1.0480x over previous
//
#include <hip/hip_runtime.h>
#include <hip/hip_bf16.h>

typedef __attribute__((ext_vector_type(8))) short short8v;
typedef __attribute__((ext_vector_type(4))) float floatx4;

__device__ __forceinline__ float bf2f(unsigned short u) {
  union { unsigned int i; float f; } c;
  c.i = ((unsigned int)u) << 16;
  return c.f;
}
__device__ __forceinline__ unsigned short f2bf(float f) {
  __hip_bfloat16 h = __float2bfloat16(f);
  return *reinterpret_cast<unsigned short*>(&h);
}

// ---------------------------------------------------------------------------
// Fused conversion: 9 jobs of fp32 [R x K] -> bf16 [R x Kp] (zero-padded).
// Job 0 (x0, 79% of elements) first so the search loop usually exits at once.
// ---------------------------------------------------------------------------
struct ConvJobs {
  const float* src[9];
  unsigned short* dst[9];
  int K[9];
  int Kp[9];
  int cum[10];
};

__global__ __launch_bounds__(256) void convert_all_kernel(ConvJobs J) {
  const int total = J.cum[9];
  for (int idx = blockIdx.x * 256 + threadIdx.x; idx < total;
       idx += gridDim.x * 256) {
    int j = 0;
    while (idx >= J.cum[j + 1]) ++j;
    const int local = idx - J.cum[j];
    const int Kp = J.Kp[j], K = J.K[j];
    const int r = local / Kp, c = local - r * Kp;
    J.dst[j][local] =
        (c < K) ? f2bf(J.src[j][(size_t)r * K + c]) : (unsigned short)0;
  }
}

// ---------------------------------------------------------------------------
// MFMA GEMM: Y[M,N] = A[M,Kp](bf16) @ B[N,Kp](bf16)^T  (+ epilogues)
// MODE 0: +bias -> bf16 out (ld=ldout)
// MODE 1: +bias, relu -> bf16 out (ld=ldout)
// MODE 2: +bias +res(fp32 ld116), LayerNorm(g,b) -> fp32 out (ld116)
//         AND bf16 out (ld128, cols 116..127 zeroed).  Requires N=116, grid.y=1.
// 128x128 tile, 256 thr = 4 waves (2x2), per-wave 4x4 frags of 16x16x32.
// LDS: A/B k-chunks of 64, XOR-swizzled 16B chunks (chunk ^= row&7).
// ---------------------------------------------------------------------------
template <int MODE>
__global__ __launch_bounds__(256) void mgemm_kernel(
    const unsigned short* __restrict__ A, const unsigned short* __restrict__ B,
    const float* __restrict__ bias, int N, int Kp, int ldout,
    unsigned short* __restrict__ Yb, float* __restrict__ Yf,
    const float* __restrict__ res, const float* __restrict__ gw,
    const float* __restrict__ bw) {
  __shared__ __align__(16) unsigned short As[128][64];
  __shared__ __align__(16) unsigned short Bs[128][64];
  __shared__ float sum1[2][128];
  __shared__ float sum2[2][128];

  const int tid = threadIdx.x;
  const int M0 = blockIdx.x * 128;
  const int N0 = blockIdx.y * 128;
  const int wid = tid >> 6, lane = tid & 63;
  const int wr = wid >> 1, wc = wid & 1;
  const int lc = lane & 15, g = lane >> 4;
  const int srow = tid >> 1, shalf = tid & 1;
  const int sw = srow & 7;

  floatx4 acc[4][4] = {};

  const int nk = Kp >> 6;
  for (int kt = 0; kt < nk; ++kt) {
    const int k0 = kt << 6;
    {
      const uint4* p = reinterpret_cast<const uint4*>(
          A + (size_t)(M0 + srow) * Kp + k0 + shalf * 32);
      uint4 v0 = p[0], v1 = p[1], v2 = p[2], v3 = p[3];
      *reinterpret_cast<uint4*>(&As[srow][((((shalf << 2) | 0) ^ sw) << 3)]) = v0;
      *reinterpret_cast<uint4*>(&As[srow][((((shalf << 2) | 1) ^ sw) << 3)]) = v1;
      *reinterpret_cast<uint4*>(&As[srow][((((shalf << 2) | 2) ^ sw) << 3)]) = v2;
      *reinterpret_cast<uint4*>(&As[srow][((((shalf << 2) | 3) ^ sw) << 3)]) = v3;
    }
    {
      uint4 v0 = {0, 0, 0, 0}, v1 = v0, v2 = v0, v3 = v0;
      const int jr = N0 + srow;
      if (jr < N) {
        const uint4* p = reinterpret_cast<const uint4*>(
            B + (size_t)jr * Kp + k0 + shalf * 32);
        v0 = p[0]; v1 = p[1]; v2 = p[2]; v3 = p[3];
      }
      *reinterpret_cast<uint4*>(&Bs[srow][((((shalf << 2) | 0) ^ sw) << 3)]) = v0;
      *reinterpret_cast<uint4*>(&Bs[srow][((((shalf << 2) | 1) ^ sw) << 3)]) = v1;
      *reinterpret_cast<uint4*>(&Bs[srow][((((shalf << 2) | 2) ^ sw) << 3)]) = v2;
      *reinterpret_cast<uint4*>(&Bs[srow][((((shalf << 2) | 3) ^ sw) << 3)]) = v3;
    }
    __syncthreads();
#pragma unroll
    for (int ks = 0; ks < 2; ++ks) {
      short8v a[4], b[4];
#pragma unroll
      for (int m = 0; m < 4; ++m) {
        const int row = wr * 64 + m * 16 + lc;
        a[m] = *reinterpret_cast<const short8v*>(
            &As[row][((((ks << 2) | g) ^ (lc & 7)) << 3)]);
      }
#pragma unroll
      for (int n = 0; n < 4; ++n) {
        const int col = wc * 64 + n * 16 + lc;
        b[n] = *reinterpret_cast<const short8v*>(
            &Bs[col][((((ks << 2) | g) ^ (lc & 7)) << 3)]);
      }
#pragma unroll
      for (int m = 0; m < 4; ++m)
#pragma unroll
        for (int n = 0; n < 4; ++n)
          acc[m][n] = __builtin_amdgcn_mfma_f32_16x16x32_bf16(a[m], b[n],
                                                              acc[m][n], 0, 0, 0);
    }
    __syncthreads();
  }

  if constexpr (MODE != 2) {
#pragma unroll
    for (int m = 0; m < 4; ++m) {
#pragma unroll
      for (int r = 0; r < 4; ++r) {
        const int row = M0 + wr * 64 + m * 16 + g * 4 + r;
#pragma unroll
        for (int n = 0; n < 4; ++n) {
          const int col = N0 + wc * 64 + n * 16 + lc;
          if (col < N) {
            float v = acc[m][n][r] + bias[col];
            if (MODE == 1) v = fmaxf(v, 0.f);
            Yb[(size_t)row * ldout + col] = f2bf(v);
          }
        }
      }
    }
  } else {
    float s1l[4][4], s2l[4][4];
#pragma unroll
    for (int m = 0; m < 4; ++m) {
#pragma unroll
      for (int r = 0; r < 4; ++r) {
        const int row = M0 + wr * 64 + m * 16 + g * 4 + r;
        float s = 0.f, s2 = 0.f;
#pragma unroll
        for (int n = 0; n < 4; ++n) {
          const int col = wc * 64 + n * 16 + lc;
          float v = 0.f;
          if (col < 116)
            v = acc[m][n][r] + bias[col] + res[(size_t)row * 116 + col];
          acc[m][n][r] = v;
          s += v;
          s2 = fmaf(v, v, s2);
        }
#pragma unroll
        for (int st = 1; st < 16; st <<= 1) {
          s += __shfl_xor(s, st, 16);
          s2 += __shfl_xor(s2, st, 16);
        }
        s1l[m][r] = s;
        s2l[m][r] = s2;
      }
    }
    if (lc == 0) {
#pragma unroll
      for (int m = 0; m < 4; ++m)
#pragma unroll
        for (int r = 0; r < 4; ++r) {
          const int lrow = wr * 64 + m * 16 + g * 4 + r;
          sum1[wc][lrow] = s1l[m][r];
          sum2[wc][lrow] = s2l[m][r];
        }
    }
    __syncthreads();
#pragma unroll
    for (int m = 0; m < 4; ++m) {
#pragma unroll
      for (int r = 0; r < 4; ++r) {
        const int lrow = wr * 64 + m * 16 + g * 4 + r;
        const int row = M0 + lrow;
        const float st = sum1[0][lrow] + sum1[1][lrow];
        const float s2t = sum2[0][lrow] + sum2[1][lrow];
        const float mean = st * (1.f / 116.f);
        const float var = s2t * (1.f / 116.f) - mean * mean;
        const float rstd = 1.f / sqrtf(var + 1e-5f);
#pragma unroll
        for (int n = 0; n < 4; ++n) {
          const int col = wc * 64 + n * 16 + lc;
          if (col < 116) {
            const float y = (acc[m][n][r] - mean) * rstd * gw[col] + bw[col];
            Yf[(size_t)row * 116 + col] = y;
            Yb[(size_t)row * 128 + col] = f2bf(y);
          } else {
            Yb[(size_t)row * 128 + col] = 0;
          }
        }
      }
    }
  }
}

// ---------------------------------------------------------------------------
// Attention: one block = one (n,h), 64 threads (one per query row s).
// ---------------------------------------------------------------------------
__global__ __launch_bounds__(64) void attn_kernel(
    const unsigned short* __restrict__ qkv, unsigned short* __restrict__ obuf) {
  const int h = blockIdx.x & 3;
  const int n = blockIdx.x >> 2;
  const int s = threadIdx.x;
  __shared__ float ks[64][30];
  __shared__ float vs[64][30];

  const size_t base = ((size_t)s * 512 + n) * 348 + h * 29;
  float q[29];
#pragma unroll
  for (int d = 0; d < 29; ++d) {
    q[d] = bf2f(qkv[base + d]);
    ks[s][d] = bf2f(qkv[base + 116 + d]);
    vs[s][d] = bf2f(qkv[base + 232 + d]);
  }
  __syncthreads();

  const float scale = 0.18569533817705186f;  // 1/sqrt(29)
  float sc[64];
#pragma unroll
  for (int t = 0; t < 64; ++t) {
    float a = 0.f;
#pragma unroll
    for (int d = 0; d < 29; ++d) a = fmaf(q[d], ks[t][d], a);
    sc[t] = a * scale;
  }
  float m = sc[0];
#pragma unroll
  for (int t = 1; t < 64; ++t) m = fmaxf(m, sc[t]);
  float sum = 0.f;
#pragma unroll
  for (int t = 0; t < 64; ++t) {
    sc[t] = __expf(sc[t] - m);
    sum += sc[t];
  }
  const float inv = 1.f / sum;
  float o[29] = {};
#pragma unroll
  for (int t = 0; t < 64; ++t) {
    const float p = sc[t];
#pragma unroll
    for (int d = 0; d < 29; ++d) o[d] = fmaf(p, vs[t][d], o[d]);
  }
  const size_t ob = ((size_t)s * 512 + n) * 128 + h * 29;
#pragma unroll
  for (int d = 0; d < 29; ++d) obuf[ob + d] = f2bf(o[d] * inv);
  if (h == 3) {
    const size_t pb = ((size_t)s * 512 + n) * 128;
#pragma unroll
    for (int c = 116; c < 128; ++c) obuf[pb + c] = 0;
  }
}

// ---------------------------------------------------------------------------
// fc: feas[b,h,e] = sum_t x4[b,t,e] * fc_w[h,t] + fc_b[h]   (fp32)
// ---------------------------------------------------------------------------
__global__ __launch_bounds__(256) void fc_kernel(const float* __restrict__ X4,
                                                 const float* __restrict__ fw,
                                                 const float* __restrict__ fb,
                                                 float* __restrict__ fea) {
  const int eg = blockIdx.x;  // 0..3
  const int b = blockIdx.y;   // 0..63
  const int e0 = eg * 29;
  __shared__ float Os[64][30];
  __shared__ float Wf[64][65];
  const int tid = threadIdx.x;
  const int h = tid & 63, jg = tid >> 6;
  float acc[8] = {};

  for (int tc = 0; tc < 8; ++tc) {
    for (int idx = tid; idx < 64 * 29; idx += 256) {
      int tt = idx / 29;
      int ee = idx - tt * 29;
      Os[tt][ee] = X4[((size_t)b * 512 + tc * 64 + tt) * 116 + e0 + ee];
    }
    for (int idx = tid; idx < 64 * 64; idx += 256) {
      int hh = idx >> 6, t2 = idx & 63;
      Wf[hh][t2] = fw[(size_t)hh * 512 + tc * 64 + t2];
    }
    __syncthreads();
#pragma unroll 4
    for (int t = 0; t < 64; ++t) {
      const float w = Wf[h][t];
#pragma unroll
      for (int m = 0; m < 8; ++m) {
        const int el = jg + 4 * m;
        if (el < 29) acc[m] = fmaf(Os[t][el], w, acc[m]);
      }
    }
    __syncthreads();
  }
  const float bb = fb[h];
#pragma unroll
  for (int m = 0; m < 8; ++m) {
    const int el = jg + 4 * m;
    if (el < 29) fea[((size_t)b * 64 + h) * 116 + e0 + el] = acc[m] + bb;
  }
}

// ---------------------------------------------------------------------------
// Similarity via MFMA with LDS-staged vectorized output.
// Block per (b,a).  Phase 1: stage transposed bf16 tiles Ft/St (swizzled).
// Phase 2: fn/sn column norms.  Phase 3: MFMA dot (4 waves 2x2, 4x3 frags).
// Phase 4: divide by denom, scatter result tile to LDS (reusing Ft/St space),
// then write BOTH outputs as contiguous float4 streams (each (b,a) tile is a
// contiguous 41,760 B region of simil/similar).
// ---------------------------------------------------------------------------
__global__ __launch_bounds__(256) void sim_mfma_kernel(
    const float* __restrict__ fea, const float* __restrict__ simin,
    float* __restrict__ simil, float* __restrict__ similar) {
  const int a = blockIdx.x;  // 0..115
  const int b = blockIdx.y;  // 0..63
  __shared__ __align__(16) unsigned char shmem[41760];  // Ft+St, later Rs
  __shared__ float fnrow[116];
  __shared__ float snrow[90];
  __shared__ float wred[4];
  const int tid = threadIdx.x;

  unsigned short (*Ft)[64] = reinterpret_cast<unsigned short(*)[64]>(shmem);
  unsigned short (*St)[64] =
      reinterpret_cast<unsigned short(*)[64]>(shmem + 16384);
  float* Rs = reinterpret_cast<float*>(shmem);  // [10440] after MFMA

  // stage + transpose + bf16-convert (coalesced global reads)
  for (int idx = tid; idx < 64 * 116; idx += 256) {
    const int h = idx / 116, d = idx - h * 116;
    Ft[d][(((h >> 3) ^ (d & 7)) << 3) | (h & 7)] =
        f2bf(fea[((size_t)b * 64 + h) * 116 + d]);
  }
  for (int idx = tid; idx < 12 * 64; idx += 256) {
    const int d = 116 + (idx >> 6), h = idx & 63;
    Ft[d][(((h >> 3) ^ (d & 7)) << 3) | (h & 7)] = 0;
  }
  for (int idx = tid; idx < 64 * 90; idx += 256) {
    const int h = idx / 90, c = idx - h * 90;
    St[c][(((h >> 3) ^ (c & 7)) << 3) | (h & 7)] =
        f2bf(simin[((size_t)a * 64 + h) * 90 + c]);
  }
  for (int idx = tid; idx < 6 * 64; idx += 256) {
    const int c = 90 + (idx >> 6), h = idx & 63;
    St[c][(((h >> 3) ^ (c & 7)) << 3) | (h & 7)] = 0;
  }
  __syncthreads();

  // column norms from the staged bf16 tiles (matches dot operands)
  if (tid < 116) {
    const int d = tid;
    float s = 0.f;
#pragma unroll 8
    for (int h = 0; h < 64; ++h) {
      const float t = bf2f(Ft[d][(((h >> 3) ^ (d & 7)) << 3) | (h & 7)]);
      s = fmaf(t, t, s);
    }
    fnrow[d] = sqrtf(s);
  } else if (tid >= 128 && tid < 218) {
    const int c = tid - 128;
    float s = 0.f;
#pragma unroll 8
    for (int h = 0; h < 64; ++h) {
      const float t = bf2f(St[c][(((h >> 3) ^ (c & 7)) << 3) | (h & 7)]);
      s = fmaf(t, t, s);
    }
    snrow[c] = sqrtf(s);
  }
  __syncthreads();

  const int wid = tid >> 6, lane = tid & 63;
  const int wr = wid >> 1, wc = wid & 1;   // wave tile: rows wr*64, cols wc*48
  const int lc = lane & 15, g = lane >> 4;

  floatx4 acc[4][3] = {};
#pragma unroll
  for (int ks = 0; ks < 2; ++ks) {
    short8v av[4], bv[3];
#pragma unroll
    for (int m = 0; m < 4; ++m) {
      const int row = wr * 64 + m * 16 + lc;
      av[m] = *reinterpret_cast<const short8v*>(
          &Ft[row][((((ks << 2) | g) ^ (lc & 7)) << 3)]);
    }
#pragma unroll
    for (int n = 0; n < 3; ++n) {
      const int col = wc * 48 + n * 16 + lc;
      bv[n] = *reinterpret_cast<const short8v*>(
          &St[col][((((ks << 2) | g) ^ (lc & 7)) << 3)]);
    }
#pragma unroll
    for (int m = 0; m < 4; ++m)
#pragma unroll
      for (int n = 0; n < 3; ++n)
        acc[m][n] = __builtin_amdgcn_mfma_f32_16x16x32_bf16(av[m], bv[n],
                                                            acc[m][n], 0, 0, 0);
  }
  __syncthreads();  // all LDS reads done; Ft/St space becomes Rs

  // divide by denom, accumulate row-norm ss, scatter to Rs
  float ss = 0.f;
#pragma unroll
  for (int m = 0; m < 4; ++m) {
#pragma unroll
    for (int r = 0; r < 4; ++r) {
      const int d = wr * 64 + m * 16 + g * 4 + r;
      if (d < 116) {
        const float fn = fnrow[d];
#pragma unroll
        for (int n = 0; n < 3; ++n) {
          const int c = wc * 48 + n * 16 + lc;
          if (c < 90) {
            const float denom = fmaxf(fn * snrow[c], 1e-8f);
            float rcp = __builtin_amdgcn_rcpf(denom);
            rcp = rcp * (2.0f - denom * rcp);  // 1 Newton step
            const float v = acc[m][n][r] * rcp;
            ss = fmaf(v, v, ss);
            Rs[d * 90 + c] = v;
          }
        }
      }
    }
  }
#pragma unroll
  for (int st = 1; st <= 32; st <<= 1) ss += __shfl_xor(ss, st, 64);
  if (lane == 0) wred[wid] = ss;
  __syncthreads();
  const float tot = wred[0] + wred[1] + wred[2] + wred[3];
  const float inv = 1.f / fmaxf(sqrtf(tot), 1e-12f);

  // vectorized contiguous writes of both outputs
  const size_t rowbase = ((size_t)b * 116 + a) * (116 * 90);
  float4* so = reinterpret_cast<float4*>(simil + rowbase);
  float4* sr = reinterpret_cast<float4*>(similar + rowbase);
  const float4* rs4 = reinterpret_cast<const float4*>(Rs);
  for (int i = tid; i < 2610; i += 256) {
    float4 v = rs4[i];
    so[i] = v;
    float4 w;
    w.x = v.x * inv; w.y = v.y * inv; w.z = v.z * inv; w.w = v.w * inv;
    sr[i] = w;
  }
}

// ---------------------------------------------------------------------------
extern "C" void kernel_launch(void* const* d_in, const int* in_sizes, int n_in,
                              void* d_out, int out_size, void* d_ws,
                              size_t ws_size, hipStream_t stream) {
  const float* x0 = (const float*)d_in[0];
  const float* simin = (const float*)d_in[1];
  const float* p[24];
  for (int i = 0; i < 24; ++i) p[i] = (const float*)d_in[2 + i];
  const float* fc_w = (const float*)d_in[26];
  const float* fc_b = (const float*)d_in[27];

  float* out = (float*)d_out;
  float* fea = out;
  float* simil = out + 475136;       // 64*116*116*90 = 77,506,560 floats
  float* similar = out + 77981696;   // 475136 + 77506560

  // scratch in 'similar' region (dead before sim_mfma_kernel writes it):
  float* xa_f[2] = {similar + 0, similar + 7602176};
  float* xb_f[2] = {similar + 3801088, similar + 11403264};
  unsigned short* Ab = (unsigned short*)(similar + 15204352);     // 32768x128
  unsigned short* obufb = (unsigned short*)(similar + 17301504);  // 32768x128
  unsigned short* xab[2] = {(unsigned short*)(similar + 19398656),
                            (unsigned short*)(similar + 23592960)};
  unsigned short* xbb[2] = {(unsigned short*)(similar + 21495808),
                            (unsigned short*)(similar + 25690112)};
  unsigned short* qkvb = (unsigned short*)(similar + 27787264);   // 32768x348
  // scratch in 'simil' region:
  unsigned short* hbufb = (unsigned short*)simil;                 // 32768x2048
  unsigned short* wbuf = (unsigned short*)(simil + 33554432);
  const size_t WSZ = 559104;  // wqkv 44544 + wo 14848 + w1 262144 + w2 237568

  // single fused conversion kernel (9 jobs)
  {
    ConvJobs J;
    int cum = 0;
    auto add = [&](int j, const float* s, unsigned short* dd, int R, int K,
                   int Kp) {
      J.src[j] = s; J.dst[j] = dd; J.K[j] = K; J.Kp[j] = Kp;
      J.cum[j] = cum; cum += R * Kp;
    };
    add(0, x0, Ab, 32768, 116, 128);
    for (int L = 0; L < 2; ++L) {
      unsigned short* wb = wbuf + L * WSZ;
      add(1 + L * 4, p[L * 12 + 0], wb + 0, 348, 116, 128);
      add(2 + L * 4, p[L * 12 + 2], wb + 44544, 116, 116, 128);
      add(3 + L * 4, p[L * 12 + 6], wb + 59392, 2048, 116, 128);
      add(4 + L * 4, p[L * 12 + 8], wb + 321536, 116, 2048, 2048);
    }
    J.cum[9] = cum;
    hipLaunchKernelGGL(convert_all_kernel, dim3(2048), dim3(256), 0, stream, J);
  }

  const unsigned short* Ain = Ab;
  const float* resin = x0;
  for (int L = 0; L < 2; ++L) {
    unsigned short* wb = wbuf + L * WSZ;
    const float* bqkv = p[L * 12 + 1];
    const float* bo = p[L * 12 + 3];
    const float* g1 = p[L * 12 + 4];
    const float* bn1 = p[L * 12 + 5];
    const float* b1 = p[L * 12 + 7];
    const float* b2 = p[L * 12 + 9];
    const float* g2 = p[L * 12 + 10];
    const float* bn2 = p[L * 12 + 11];

    hipLaunchKernelGGL((mgemm_kernel<0>), dim3(256, 3), dim3(256), 0, stream,
                       Ain, wb + 0, bqkv, 348, 128, 348, qkvb, (float*)nullptr,
                       (const float*)nullptr, (const float*)nullptr,
                       (const float*)nullptr);
    hipLaunchKernelGGL(attn_kernel, dim3(2048), dim3(64), 0, stream, qkvb,
                       obufb);
    hipLaunchKernelGGL((mgemm_kernel<2>), dim3(256, 1), dim3(256), 0, stream,
                       obufb, wb + 44544, bo, 116, 128, 0, xab[L], xa_f[L],
                       resin, g1, bn1);
    hipLaunchKernelGGL((mgemm_kernel<1>), dim3(256, 16), dim3(256), 0, stream,
                       xab[L], wb + 59392, b1, 2048, 128, 2048, hbufb,
                       (float*)nullptr, (const float*)nullptr,
                       (const float*)nullptr, (const float*)nullptr);
    hipLaunchKernelGGL((mgemm_kernel<2>), dim3(256, 1), dim3(256), 0, stream,
                       hbufb, wb + 321536, b2, 116, 2048, 0, xbb[L], xb_f[L],
                       xa_f[L], g2, bn2);
    Ain = xbb[L];
    resin = xb_f[L];
  }

  hipLaunchKernelGGL(fc_kernel, dim3(4, 64), dim3(256), 0, stream, xb_f[1],
                     fc_w, fc_b, fea);
  hipLaunchKernelGGL(sim_mfma_kernel, dim3(116, 64), dim3(256), 0, stream, fea,
                     simin, simil, similar);
}

// Round 6
// 754.519 us; speedup vs baseline: 5.2695x; 1.0429x over previous
//
#include <hip/hip_runtime.h>
#include <hip/hip_bf16.h>

typedef __attribute__((ext_vector_type(8))) short short8v;
typedef __attribute__((ext_vector_type(4))) float floatx4;
typedef unsigned short ushort_t;

__device__ __forceinline__ float bf2f(unsigned short u) {
  union { unsigned int i; float f; } c;
  c.i = ((unsigned int)u) << 16;
  return c.f;
}
__device__ __forceinline__ unsigned short f2bf(float f) {
  __hip_bfloat16 h = __float2bfloat16(f);
  return *reinterpret_cast<unsigned short*>(&h);
}

// ---------------------------------------------------------------------------
// Fused conversion: 9 jobs fp32 -> bf16.
// mode 0: [R x K] -> [R x Kp] zero-padded tail.
// mode 1: wo spread: src [116 x 116] (col e=h*29+d) -> dst [116 x 128]
//         (col h*32+d, d=29..31 zero).
// ---------------------------------------------------------------------------
struct ConvJobs {
  const float* src[9];
  unsigned short* dst[9];
  int K[9];
  int Kp[9];
  int mode[9];
  int cum[10];
};

__global__ __launch_bounds__(256) void convert_all_kernel(ConvJobs J) {
  const int total = J.cum[9];
  for (int idx = blockIdx.x * 256 + threadIdx.x; idx < total;
       idx += gridDim.x * 256) {
    int j = 0;
    while (idx >= J.cum[j + 1]) ++j;
    const int local = idx - J.cum[j];
    const int Kp = J.Kp[j];
    const int r = local / Kp, c = local - r * Kp;
    unsigned short v;
    if (J.mode[j] == 0) {
      v = (c < J.K[j]) ? f2bf(J.src[j][(size_t)r * J.K[j] + c])
                       : (unsigned short)0;
    } else {
      const int h = c >> 5, d = c & 31;
      v = (d < 29) ? f2bf(J.src[j][(size_t)r * 116 + h * 29 + d])
                   : (unsigned short)0;
    }
    J.dst[j][local] = v;
  }
}

// ---------------------------------------------------------------------------
// MFMA GEMM 128x128 tile: Y = A[M,Kp] @ B[N,Kp]^T + bias
// MODE 0: bf16 out, ld=ldout.  MODE 1: +relu.  MODE 3: qkv head-major output
//   qkvp[which][n][h][s][32], which=col/116, h=(col%116)/29, n=row&511,
//   s=row>>9.
// ---------------------------------------------------------------------------
template <int MODE>
__global__ __launch_bounds__(256) void mgemm_kernel(
    const unsigned short* __restrict__ A, const unsigned short* __restrict__ B,
    const float* __restrict__ bias, int N, int Kp, int ldout,
    unsigned short* __restrict__ Yb) {
  __shared__ __align__(16) unsigned short As[128][64];
  __shared__ __align__(16) unsigned short Bs[128][64];

  const int tid = threadIdx.x;
  const int M0 = blockIdx.x * 128;
  const int N0 = blockIdx.y * 128;
  const int wid = tid >> 6, lane = tid & 63;
  const int wr = wid >> 1, wc = wid & 1;
  const int lc = lane & 15, g = lane >> 4;
  const int srow = tid >> 1, shalf = tid & 1;
  const int sw = srow & 7;

  floatx4 acc[4][4] = {};

  const int nk = Kp >> 6;
  for (int kt = 0; kt < nk; ++kt) {
    const int k0 = kt << 6;
    {
      const uint4* p = reinterpret_cast<const uint4*>(
          A + (size_t)(M0 + srow) * Kp + k0 + shalf * 32);
      uint4 v0 = p[0], v1 = p[1], v2 = p[2], v3 = p[3];
      *reinterpret_cast<uint4*>(&As[srow][((((shalf << 2) | 0) ^ sw) << 3)]) = v0;
      *reinterpret_cast<uint4*>(&As[srow][((((shalf << 2) | 1) ^ sw) << 3)]) = v1;
      *reinterpret_cast<uint4*>(&As[srow][((((shalf << 2) | 2) ^ sw) << 3)]) = v2;
      *reinterpret_cast<uint4*>(&As[srow][((((shalf << 2) | 3) ^ sw) << 3)]) = v3;
    }
    {
      uint4 v0 = {0, 0, 0, 0}, v1 = v0, v2 = v0, v3 = v0;
      const int jr = N0 + srow;
      if (jr < N) {
        const uint4* p = reinterpret_cast<const uint4*>(
            B + (size_t)jr * Kp + k0 + shalf * 32);
        v0 = p[0]; v1 = p[1]; v2 = p[2]; v3 = p[3];
      }
      *reinterpret_cast<uint4*>(&Bs[srow][((((shalf << 2) | 0) ^ sw) << 3)]) = v0;
      *reinterpret_cast<uint4*>(&Bs[srow][((((shalf << 2) | 1) ^ sw) << 3)]) = v1;
      *reinterpret_cast<uint4*>(&Bs[srow][((((shalf << 2) | 2) ^ sw) << 3)]) = v2;
      *reinterpret_cast<uint4*>(&Bs[srow][((((shalf << 2) | 3) ^ sw) << 3)]) = v3;
    }
    __syncthreads();
#pragma unroll
    for (int ks = 0; ks < 2; ++ks) {
      short8v a[4], b[4];
#pragma unroll
      for (int m = 0; m < 4; ++m) {
        const int row = wr * 64 + m * 16 + lc;
        a[m] = *reinterpret_cast<const short8v*>(
            &As[row][((((ks << 2) | g) ^ (lc & 7)) << 3)]);
      }
#pragma unroll
      for (int n = 0; n < 4; ++n) {
        const int col = wc * 64 + n * 16 + lc;
        b[n] = *reinterpret_cast<const short8v*>(
            &Bs[col][((((ks << 2) | g) ^ (lc & 7)) << 3)]);
      }
#pragma unroll
      for (int m = 0; m < 4; ++m)
#pragma unroll
        for (int n = 0; n < 4; ++n)
          acc[m][n] = __builtin_amdgcn_mfma_f32_16x16x32_bf16(a[m], b[n],
                                                              acc[m][n], 0, 0, 0);
    }
    __syncthreads();
  }

#pragma unroll
  for (int m = 0; m < 4; ++m) {
#pragma unroll
    for (int r = 0; r < 4; ++r) {
      const int row = M0 + wr * 64 + m * 16 + g * 4 + r;
#pragma unroll
      for (int n = 0; n < 4; ++n) {
        const int col = N0 + wc * 64 + n * 16 + lc;
        if (col < N) {
          float v = acc[m][n][r] + bias[col];
          if (MODE == 1) v = fmaxf(v, 0.f);
          if constexpr (MODE == 3) {
            const int which = (col >= 232) ? 2 : (col >= 116 ? 1 : 0);
            const int cw = col - which * 116;
            const int h = (cw * 565) >> 14;
            const int d = cw - h * 29;
            const int nn2 = row & 511, ss = row >> 9;
            Yb[(size_t)which * 4194304 +
               ((((size_t)nn2 * 4 + h) * 64 + ss) << 5) + d] = f2bf(v);
          } else {
            Yb[(size_t)row * ldout + col] = f2bf(v);
          }
        }
      }
    }
  }
}

// ---------------------------------------------------------------------------
// 64-row-tile GEMM + residual + LayerNorm (N=116).  grid 512 blocks.
// out: Yf fp32 [tok][116] and Yb bf16 [tok][128] (pad cols zero).
// ---------------------------------------------------------------------------
__global__ __launch_bounds__(256) void mgemm64_ln_kernel(
    const unsigned short* __restrict__ A, const unsigned short* __restrict__ B,
    const float* __restrict__ bias, int Kp, unsigned short* __restrict__ Yb,
    float* __restrict__ Yf, const float* __restrict__ res,
    const float* __restrict__ gw, const float* __restrict__ bw) {
  __shared__ __align__(16) unsigned short As[64][64];
  __shared__ __align__(16) unsigned short Bs[128][64];
  __shared__ float sum1[2][64];
  __shared__ float sum2[2][64];

  const int tid = threadIdx.x;
  const int M0 = blockIdx.x * 64;
  const int wid = tid >> 6, lane = tid & 63;
  const int wr = wid >> 1, wc = wid & 1;
  const int lc = lane & 15, g = lane >> 4;
  const int arow = tid >> 2, aq = tid & 3;
  const int brow = tid >> 1, bhalf = tid & 1;

  floatx4 acc[2][4] = {};

  const int nk = Kp >> 6;
  for (int kt = 0; kt < nk; ++kt) {
    const int k0 = kt << 6;
    {
      const uint4* p = reinterpret_cast<const uint4*>(
          A + (size_t)(M0 + arow) * Kp + k0 + aq * 16);
      uint4 v0 = p[0], v1 = p[1];
      const int swa = arow & 7;
      *reinterpret_cast<uint4*>(&As[arow][(((aq * 2) ^ swa) << 3)]) = v0;
      *reinterpret_cast<uint4*>(&As[arow][(((aq * 2 + 1) ^ swa) << 3)]) = v1;
    }
    {
      uint4 v0 = {0, 0, 0, 0}, v1 = v0, v2 = v0, v3 = v0;
      if (brow < 116) {
        const uint4* p = reinterpret_cast<const uint4*>(
            B + (size_t)brow * Kp + k0 + bhalf * 32);
        v0 = p[0]; v1 = p[1]; v2 = p[2]; v3 = p[3];
      }
      const int sw = brow & 7;
      *reinterpret_cast<uint4*>(&Bs[brow][((((bhalf << 2) | 0) ^ sw) << 3)]) = v0;
      *reinterpret_cast<uint4*>(&Bs[brow][((((bhalf << 2) | 1) ^ sw) << 3)]) = v1;
      *reinterpret_cast<uint4*>(&Bs[brow][((((bhalf << 2) | 2) ^ sw) << 3)]) = v2;
      *reinterpret_cast<uint4*>(&Bs[brow][((((bhalf << 2) | 3) ^ sw) << 3)]) = v3;
    }
    __syncthreads();
#pragma unroll
    for (int ks = 0; ks < 2; ++ks) {
      short8v a[2], b[4];
#pragma unroll
      for (int m = 0; m < 2; ++m) {
        const int row = wr * 32 + m * 16 + lc;
        a[m] = *reinterpret_cast<const short8v*>(
            &As[row][((((ks << 2) | g) ^ (row & 7)) << 3)]);
      }
#pragma unroll
      for (int n = 0; n < 4; ++n) {
        const int col = wc * 64 + n * 16 + lc;
        b[n] = *reinterpret_cast<const short8v*>(
            &Bs[col][((((ks << 2) | g) ^ (col & 7)) << 3)]);
      }
#pragma unroll
      for (int m = 0; m < 2; ++m)
#pragma unroll
        for (int n = 0; n < 4; ++n)
          acc[m][n] = __builtin_amdgcn_mfma_f32_16x16x32_bf16(a[m], b[n],
                                                              acc[m][n], 0, 0, 0);
    }
    __syncthreads();
  }

  float s1l[2][4], s2l[2][4];
#pragma unroll
  for (int m = 0; m < 2; ++m) {
#pragma unroll
    for (int r = 0; r < 4; ++r) {
      const int row = M0 + wr * 32 + m * 16 + g * 4 + r;
      float s = 0.f, s2 = 0.f;
#pragma unroll
      for (int n = 0; n < 4; ++n) {
        const int col = wc * 64 + n * 16 + lc;
        float v = 0.f;
        if (col < 116)
          v = acc[m][n][r] + bias[col] + res[(size_t)row * 116 + col];
        acc[m][n][r] = v;
        s += v;
        s2 = fmaf(v, v, s2);
      }
#pragma unroll
      for (int st = 1; st < 16; st <<= 1) {
        s += __shfl_xor(s, st, 16);
        s2 += __shfl_xor(s2, st, 16);
      }
      s1l[m][r] = s;
      s2l[m][r] = s2;
    }
  }
  if (lc == 0) {
#pragma unroll
    for (int m = 0; m < 2; ++m)
#pragma unroll
      for (int r = 0; r < 4; ++r) {
        const int lrow = wr * 32 + m * 16 + g * 4 + r;
        sum1[wc][lrow] = s1l[m][r];
        sum2[wc][lrow] = s2l[m][r];
      }
  }
  __syncthreads();
#pragma unroll
  for (int m = 0; m < 2; ++m) {
#pragma unroll
    for (int r = 0; r < 4; ++r) {
      const int lrow = wr * 32 + m * 16 + g * 4 + r;
      const int row = M0 + lrow;
      const float st = sum1[0][lrow] + sum1[1][lrow];
      const float s2t = sum2[0][lrow] + sum2[1][lrow];
      const float mean = st * (1.f / 116.f);
      const float var = s2t * (1.f / 116.f) - mean * mean;
      const float rstd = 1.f / sqrtf(var + 1e-5f);
#pragma unroll
      for (int n = 0; n < 4; ++n) {
        const int col = wc * 64 + n * 16 + lc;
        if (col < 116) {
          const float y = (acc[m][n][r] - mean) * rstd * gw[col] + bw[col];
          Yf[(size_t)row * 116 + col] = y;
          Yb[(size_t)row * 128 + col] = f2bf(y);
        } else {
          Yb[(size_t)row * 128 + col] = 0;
        }
      }
    }
  }
}

// ---------------------------------------------------------------------------
// Attention, head-major coalesced I/O.  Block (n,h), 64 threads (lane = s).
// qkvp[which][(n*4+h)*64+s][32] bf16.  obuf[tok][128] bf16, cols h*32+d.
// ---------------------------------------------------------------------------
__global__ __launch_bounds__(64) void attn_kernel(
    const unsigned short* __restrict__ qkvp, unsigned short* __restrict__ obuf) {
  const int h = blockIdx.x & 3;
  const int n = blockIdx.x >> 2;
  const int s = threadIdx.x;
  __shared__ float ks[64][36];
  __shared__ float vs[64][36];

  const size_t rb = (((size_t)n * 4 + h) * 64 + s) * 32;
  const uint4* qp = reinterpret_cast<const uint4*>(qkvp + rb);
  const uint4* kp = reinterpret_cast<const uint4*>(qkvp + 4194304 + rb);
  const uint4* vp = reinterpret_cast<const uint4*>(qkvp + 8388608 + rb);
  uint4 qv[4], kv4[4], vv4[4];
#pragma unroll
  for (int i = 0; i < 4; ++i) {
    qv[i] = qp[i];
    kv4[i] = kp[i];
    vv4[i] = vp[i];
  }
  float q[32], kf[32], vf[32];
#pragma unroll
  for (int i = 0; i < 4; ++i) {
    const unsigned* wq = reinterpret_cast<const unsigned*>(&qv[i]);
    const unsigned* wk = reinterpret_cast<const unsigned*>(&kv4[i]);
    const unsigned* wv = reinterpret_cast<const unsigned*>(&vv4[i]);
#pragma unroll
    for (int j = 0; j < 4; ++j) {
      union { unsigned u; float f; } lo, hi;
      const int d0 = i * 8 + 2 * j;
      lo.u = wq[j] << 16; hi.u = wq[j] & 0xffff0000u;
      q[d0] = lo.f; q[d0 + 1] = hi.f;
      lo.u = wk[j] << 16; hi.u = wk[j] & 0xffff0000u;
      kf[d0] = (d0 < 29) ? lo.f : 0.f;
      kf[d0 + 1] = (d0 + 1 < 29) ? hi.f : 0.f;
      lo.u = wv[j] << 16; hi.u = wv[j] & 0xffff0000u;
      vf[d0] = (d0 < 29) ? lo.f : 0.f;
      vf[d0 + 1] = (d0 + 1 < 29) ? hi.f : 0.f;
    }
  }
  q[29] = q[30] = q[31] = 0.f;
#pragma unroll
  for (int c = 0; c < 8; ++c) {
    *reinterpret_cast<float4*>(&ks[s][c * 4]) =
        make_float4(kf[4 * c], kf[4 * c + 1], kf[4 * c + 2], kf[4 * c + 3]);
    *reinterpret_cast<float4*>(&vs[s][c * 4]) =
        make_float4(vf[4 * c], vf[4 * c + 1], vf[4 * c + 2], vf[4 * c + 3]);
  }
  __syncthreads();

  const float scale = 0.18569533817705186f;  // 1/sqrt(29)
  float sc[64];
#pragma unroll 4
  for (int t = 0; t < 64; ++t) {
    const float4* kr = reinterpret_cast<const float4*>(&ks[t][0]);
    float a = 0.f;
#pragma unroll
    for (int c = 0; c < 8; ++c) {
      const float4 kc = kr[c];
      a = fmaf(q[4 * c], kc.x, a);
      a = fmaf(q[4 * c + 1], kc.y, a);
      a = fmaf(q[4 * c + 2], kc.z, a);
      a = fmaf(q[4 * c + 3], kc.w, a);
    }
    sc[t] = a * scale;
  }
  float m = sc[0];
#pragma unroll
  for (int t = 1; t < 64; ++t) m = fmaxf(m, sc[t]);
  float sum = 0.f;
#pragma unroll
  for (int t = 0; t < 64; ++t) {
    sc[t] = __expf(sc[t] - m);
    sum += sc[t];
  }
  const float inv = 1.f / sum;
  float o[32] = {};
#pragma unroll 4
  for (int t = 0; t < 64; ++t) {
    const float p = sc[t];
    const float4* vr = reinterpret_cast<const float4*>(&vs[t][0]);
#pragma unroll
    for (int c = 0; c < 8; ++c) {
      const float4 vc = vr[c];
      o[4 * c] = fmaf(p, vc.x, o[4 * c]);
      o[4 * c + 1] = fmaf(p, vc.y, o[4 * c + 1]);
      o[4 * c + 2] = fmaf(p, vc.z, o[4 * c + 2]);
      o[4 * c + 3] = fmaf(p, vc.w, o[4 * c + 3]);
    }
  }
  unsigned short ow[32];
#pragma unroll
  for (int i = 0; i < 32; ++i) ow[i] = f2bf(o[i] * inv);
  uint4* od =
      reinterpret_cast<uint4*>(obuf + ((size_t)s * 512 + n) * 128 + h * 32);
  const uint4* ows = reinterpret_cast<const uint4*>(ow);
#pragma unroll
  for (int i = 0; i < 4; ++i) od[i] = ows[i];
}

// ---------------------------------------------------------------------------
// fc: feas[b,h,e] = sum_t x4[b,t,e] * fc_w[h,t] + fc_b[h]   (fp32)
// ---------------------------------------------------------------------------
__global__ __launch_bounds__(256) void fc_kernel(const float* __restrict__ X4,
                                                 const float* __restrict__ fw,
                                                 const float* __restrict__ fb,
                                                 float* __restrict__ fea) {
  const int eg = blockIdx.x;  // 0..3
  const int b = blockIdx.y;   // 0..63
  const int e0 = eg * 29;
  __shared__ float Os[64][30];
  __shared__ float Wf[64][65];
  const int tid = threadIdx.x;
  const int h = tid & 63, jg = tid >> 6;
  float acc[8] = {};

  for (int tc = 0; tc < 8; ++tc) {
    for (int idx = tid; idx < 64 * 29; idx += 256) {
      int tt = idx / 29;
      int ee = idx - tt * 29;
      Os[tt][ee] = X4[((size_t)b * 512 + tc * 64 + tt) * 116 + e0 + ee];
    }
    for (int idx = tid; idx < 64 * 64; idx += 256) {
      int hh = idx >> 6, t2 = idx & 63;
      Wf[hh][t2] = fw[(size_t)hh * 512 + tc * 64 + t2];
    }
    __syncthreads();
#pragma unroll 4
    for (int t = 0; t < 64; ++t) {
      const float w = Wf[h][t];
#pragma unroll
      for (int m = 0; m < 8; ++m) {
        const int el = jg + 4 * m;
        if (el < 29) acc[m] = fmaf(Os[t][el], w, acc[m]);
      }
    }
    __syncthreads();
  }
  const float bb = fb[h];
#pragma unroll
  for (int m = 0; m < 8; ++m) {
    const int el = jg + 4 * m;
    if (el < 29) fea[((size_t)b * 64 + h) * 116 + e0 + el] = acc[m] + bb;
  }
}

// ---------------------------------------------------------------------------
// sim prep: feaT[b][d(128)][h(64)] bf16, fn[b][128]; simT[a][c(96)][h] bf16,
// sn[a][96].  grid 180: blocks 0..63 = fea rows, 64..179 = sim rows.
// ---------------------------------------------------------------------------
__global__ __launch_bounds__(256) void sim_prep_kernel(
    const float* __restrict__ fea, const float* __restrict__ simin,
    unsigned short* __restrict__ feaT, unsigned short* __restrict__ simT,
    float* __restrict__ fn, float* __restrict__ sn) {
  __shared__ float L[64][121];
  const int blk = blockIdx.x;
  const int tid = threadIdx.x;
  if (blk < 64) {
    const int b = blk;
    for (int idx = tid; idx < 64 * 116; idx += 256) {
      const int h = idx / 116, d = idx - h * 116;
      L[h][d] = bf2f(f2bf(fea[((size_t)b * 64 + h) * 116 + d]));
    }
    __syncthreads();
    for (int idx = tid; idx < 128 * 64; idx += 256) {
      const int d = idx >> 6, h = idx & 63;
      feaT[((size_t)b * 128 + d) * 64 + h] = (d < 116) ? f2bf(L[h][d]) : 0;
    }
    if (tid < 116) {
      float s = 0.f;
#pragma unroll 8
      for (int h = 0; h < 64; ++h) {
        const float t = L[h][tid];
        s = fmaf(t, t, s);
      }
      fn[b * 128 + tid] = sqrtf(s);
    }
  } else {
    const int a = blk - 64;
    for (int idx = tid; idx < 64 * 90; idx += 256) {
      const int h = idx / 90, c = idx - h * 90;
      L[h][c] = bf2f(f2bf(simin[((size_t)a * 64 + h) * 90 + c]));
    }
    __syncthreads();
    for (int idx = tid; idx < 96 * 64; idx += 256) {
      const int c = idx >> 6, h = idx & 63;
      simT[((size_t)a * 96 + c) * 64 + h] = (c < 90) ? f2bf(L[h][c]) : 0;
    }
    if (tid < 90) {
      float s = 0.f;
#pragma unroll 8
      for (int h = 0; h < 64; ++h) {
        const float t = L[h][tid];
        s = fmaf(t, t, s);
      }
      sn[a * 96 + tid] = sqrtf(s);
    }
  }
}

// ---------------------------------------------------------------------------
// Similarity v2: staged from pre-transposed feaT/simT + precomputed norms.
// ---------------------------------------------------------------------------
__global__ __launch_bounds__(256) void sim_mfma2_kernel(
    const unsigned short* __restrict__ feaT, const unsigned short* __restrict__ simT,
    const float* __restrict__ fn, const float* __restrict__ sn,
    float* __restrict__ simil, float* __restrict__ similar) {
  const int a = blockIdx.x;  // 0..115
  const int b = blockIdx.y;  // 0..63
  __shared__ __align__(16) unsigned char shmem[41760];
  __shared__ float fnrow[116];
  __shared__ float snrow[90];
  __shared__ float wred[4];
  const int tid = threadIdx.x;

  unsigned short (*Ft)[64] = reinterpret_cast<unsigned short(*)[64]>(shmem);
  unsigned short (*St)[64] =
      reinterpret_cast<unsigned short(*)[64]>(shmem + 16384);
  float* Rs = reinterpret_cast<float*>(shmem);

  const int srow = tid >> 1, shalf = tid & 1;
  const int sw = srow & 7;
  {
    const uint4* p = reinterpret_cast<const uint4*>(
        feaT + ((size_t)b * 128 + srow) * 64 + shalf * 32);
    uint4 v0 = p[0], v1 = p[1], v2 = p[2], v3 = p[3];
    *reinterpret_cast<uint4*>(&Ft[srow][((((shalf << 2) | 0) ^ sw) << 3)]) = v0;
    *reinterpret_cast<uint4*>(&Ft[srow][((((shalf << 2) | 1) ^ sw) << 3)]) = v1;
    *reinterpret_cast<uint4*>(&Ft[srow][((((shalf << 2) | 2) ^ sw) << 3)]) = v2;
    *reinterpret_cast<uint4*>(&Ft[srow][((((shalf << 2) | 3) ^ sw) << 3)]) = v3;
  }
  if (srow < 96) {
    const uint4* p = reinterpret_cast<const uint4*>(
        simT + ((size_t)a * 96 + srow) * 64 + shalf * 32);
    uint4 v0 = p[0], v1 = p[1], v2 = p[2], v3 = p[3];
    *reinterpret_cast<uint4*>(&St[srow][((((shalf << 2) | 0) ^ sw) << 3)]) = v0;
    *reinterpret_cast<uint4*>(&St[srow][((((shalf << 2) | 1) ^ sw) << 3)]) = v1;
    *reinterpret_cast<uint4*>(&St[srow][((((shalf << 2) | 2) ^ sw) << 3)]) = v2;
    *reinterpret_cast<uint4*>(&St[srow][((((shalf << 2) | 3) ^ sw) << 3)]) = v3;
  }
  if (tid < 116) fnrow[tid] = fn[b * 128 + tid];
  else if (tid >= 128 && tid < 218) snrow[tid - 128] = sn[a * 96 + tid - 128];
  __syncthreads();

  const int wid = tid >> 6, lane = tid & 63;
  const int wr = wid >> 1, wc = wid & 1;
  const int lc = lane & 15, g = lane >> 4;

  floatx4 acc[4][3] = {};
#pragma unroll
  for (int ks = 0; ks < 2; ++ks) {
    short8v av[4], bv[3];
#pragma unroll
    for (int m = 0; m < 4; ++m) {
      const int row = wr * 64 + m * 16 + lc;
      av[m] = *reinterpret_cast<const short8v*>(
          &Ft[row][((((ks << 2) | g) ^ (lc & 7)) << 3)]);
    }
#pragma unroll
    for (int n = 0; n < 3; ++n) {
      const int col = wc * 48 + n * 16 + lc;
      bv[n] = *reinterpret_cast<const short8v*>(
          &St[col][((((ks << 2) | g) ^ (lc & 7)) << 3)]);
    }
#pragma unroll
    for (int m = 0; m < 4; ++m)
#pragma unroll
      for (int n = 0; n < 3; ++n)
        acc[m][n] = __builtin_amdgcn_mfma_f32_16x16x32_bf16(av[m], bv[n],
                                                            acc[m][n], 0, 0, 0);
  }
  __syncthreads();  // Ft/St dead; reuse as Rs

  float ss = 0.f;
#pragma unroll
  for (int m = 0; m < 4; ++m) {
#pragma unroll
    for (int r = 0; r < 4; ++r) {
      const int d = wr * 64 + m * 16 + g * 4 + r;
      if (d < 116) {
        const float fnv = fnrow[d];
#pragma unroll
        for (int n = 0; n < 3; ++n) {
          const int c = wc * 48 + n * 16 + lc;
          if (c < 90) {
            const float denom = fmaxf(fnv * snrow[c], 1e-8f);
            float rcp = __builtin_amdgcn_rcpf(denom);
            rcp = rcp * (2.0f - denom * rcp);
            const float v = acc[m][n][r] * rcp;
            ss = fmaf(v, v, ss);
            Rs[d * 90 + c] = v;
          }
        }
      }
    }
  }
#pragma unroll
  for (int st = 1; st <= 32; st <<= 1) ss += __shfl_xor(ss, st, 64);
  if (lane == 0) wred[wid] = ss;
  __syncthreads();
  const float tot = wred[0] + wred[1] + wred[2] + wred[3];
  const float inv = 1.f / fmaxf(sqrtf(tot), 1e-12f);

  const size_t rowbase = ((size_t)b * 116 + a) * (116 * 90);
  float4* so = reinterpret_cast<float4*>(simil + rowbase);
  float4* sr = reinterpret_cast<float4*>(similar + rowbase);
  const float4* rs4 = reinterpret_cast<const float4*>(Rs);
  for (int i = tid; i < 2610; i += 256) {
    float4 v = rs4[i];
    so[i] = v;
    float4 w;
    w.x = v.x * inv; w.y = v.y * inv; w.z = v.z * inv; w.w = v.w * inv;
    sr[i] = w;
  }
}

// ---------------------------------------------------------------------------
// Fallback similarity (round-5 version) if d_ws is too small.
// ---------------------------------------------------------------------------
__global__ __launch_bounds__(256) void sim_mfma_kernel(
    const float* __restrict__ fea, const float* __restrict__ simin,
    float* __restrict__ simil, float* __restrict__ similar) {
  const int a = blockIdx.x;
  const int b = blockIdx.y;
  __shared__ __align__(16) unsigned char shmem[41760];
  __shared__ float fnrow[116];
  __shared__ float snrow[90];
  __shared__ float wred[4];
  const int tid = threadIdx.x;

  unsigned short (*Ft)[64] = reinterpret_cast<unsigned short(*)[64]>(shmem);
  unsigned short (*St)[64] =
      reinterpret_cast<unsigned short(*)[64]>(shmem + 16384);
  float* Rs = reinterpret_cast<float*>(shmem);

  for (int idx = tid; idx < 64 * 116; idx += 256) {
    const int h = idx / 116, d = idx - h * 116;
    Ft[d][(((h >> 3) ^ (d & 7)) << 3) | (h & 7)] =
        f2bf(fea[((size_t)b * 64 + h) * 116 + d]);
  }
  for (int idx = tid; idx < 12 * 64; idx += 256) {
    const int d = 116 + (idx >> 6), h = idx & 63;
    Ft[d][(((h >> 3) ^ (d & 7)) << 3) | (h & 7)] = 0;
  }
  for (int idx = tid; idx < 64 * 90; idx += 256) {
    const int h = idx / 90, c = idx - h * 90;
    St[c][(((h >> 3) ^ (c & 7)) << 3) | (h & 7)] =
        f2bf(simin[((size_t)a * 64 + h) * 90 + c]);
  }
  for (int idx = tid; idx < 6 * 64; idx += 256) {
    const int c = 90 + (idx >> 6), h = idx & 63;
    St[c][(((h >> 3) ^ (c & 7)) << 3) | (h & 7)] = 0;
  }
  __syncthreads();

  if (tid < 116) {
    float s = 0.f;
#pragma unroll 8
    for (int h = 0; h < 64; ++h) {
      const float t = bf2f(Ft[tid][(((h >> 3) ^ (tid & 7)) << 3) | (h & 7)]);
      s = fmaf(t, t, s);
    }
    fnrow[tid] = sqrtf(s);
  } else if (tid >= 128 && tid < 218) {
    const int c = tid - 128;
    float s = 0.f;
#pragma unroll 8
    for (int h = 0; h < 64; ++h) {
      const float t = bf2f(St[c][(((h >> 3) ^ (c & 7)) << 3) | (h & 7)]);
      s = fmaf(t, t, s);
    }
    snrow[c] = sqrtf(s);
  }
  __syncthreads();

  const int wid = tid >> 6, lane = tid & 63;
  const int wr = wid >> 1, wc = wid & 1;
  const int lc = lane & 15, g = lane >> 4;

  floatx4 acc[4][3] = {};
#pragma unroll
  for (int ks = 0; ks < 2; ++ks) {
    short8v av[4], bv[3];
#pragma unroll
    for (int m = 0; m < 4; ++m) {
      const int row = wr * 64 + m * 16 + lc;
      av[m] = *reinterpret_cast<const short8v*>(
          &Ft[row][((((ks << 2) | g) ^ (lc & 7)) << 3)]);
    }
#pragma unroll
    for (int n = 0; n < 3; ++n) {
      const int col = wc * 48 + n * 16 + lc;
      bv[n] = *reinterpret_cast<const short8v*>(
          &St[col][((((ks << 2) | g) ^ (lc & 7)) << 3)]);
    }
#pragma unroll
    for (int m = 0; m < 4; ++m)
#pragma unroll
      for (int n = 0; n < 3; ++n)
        acc[m][n] = __builtin_amdgcn_mfma_f32_16x16x32_bf16(av[m], bv[n],
                                                            acc[m][n], 0, 0, 0);
  }
  __syncthreads();

  float ss = 0.f;
#pragma unroll
  for (int m = 0; m < 4; ++m) {
#pragma unroll
    for (int r = 0; r < 4; ++r) {
      const int d = wr * 64 + m * 16 + g * 4 + r;
      if (d < 116) {
        const float fnv = fnrow[d];
#pragma unroll
        for (int n = 0; n < 3; ++n) {
          const int c = wc * 48 + n * 16 + lc;
          if (c < 90) {
            const float denom = fmaxf(fnv * snrow[c], 1e-8f);
            float rcp = __builtin_amdgcn_rcpf(denom);
            rcp = rcp * (2.0f - denom * rcp);
            const float v = acc[m][n][r] * rcp;
            ss = fmaf(v, v, ss);
            Rs[d * 90 + c] = v;
          }
        }
      }
    }
  }
#pragma unroll
  for (int st = 1; st <= 32; st <<= 1) ss += __shfl_xor(ss, st, 64);
  if (lane == 0) wred[wid] = ss;
  __syncthreads();
  const float tot = wred[0] + wred[1] + wred[2] + wred[3];
  const float inv = 1.f / fmaxf(sqrtf(tot), 1e-12f);

  const size_t rowbase = ((size_t)b * 116 + a) * (116 * 90);
  float4* so = reinterpret_cast<float4*>(simil + rowbase);
  float4* sr = reinterpret_cast<float4*>(similar + rowbase);
  const float4* rs4 = reinterpret_cast<const float4*>(Rs);
  for (int i = tid; i < 2610; i += 256) {
    float4 v = rs4[i];
    so[i] = v;
    float4 w;
    w.x = v.x * inv; w.y = v.y * inv; w.z = v.z * inv; w.w = v.w * inv;
    sr[i] = w;
  }
}

// ---------------------------------------------------------------------------
extern "C" void kernel_launch(void* const* d_in, const int* in_sizes, int n_in,
                              void* d_out, int out_size, void* d_ws,
                              size_t ws_size, hipStream_t stream) {
  const float* x0 = (const float*)d_in[0];
  const float* simin = (const float*)d_in[1];
  const float* p[24];
  for (int i = 0; i < 24; ++i) p[i] = (const float*)d_in[2 + i];
  const float* fc_w = (const float*)d_in[26];
  const float* fc_b = (const float*)d_in[27];

  float* out = (float*)d_out;
  float* fea = out;
  float* simil = out + 475136;       // 77,506,560 floats
  float* similar = out + 77981696;   // 475136 + 77506560

  // scratch in 'similar' region (all dead before sim writes it):
  float* xa_f[2] = {similar + 0, similar + 7602176};
  float* xb_f[2] = {similar + 3801088, similar + 11403264};
  unsigned short* obufb = (unsigned short*)(similar + 15204352);  // 4.19M ush
  unsigned short* qkvp = (unsigned short*)(similar + 17301504);   // 12.58M ush
  unsigned short* Ab = (unsigned short*)(similar + 23592960);     // 4.19M ush
  unsigned short* xab[2] = {(unsigned short*)(similar + 25690112),
                            (unsigned short*)(similar + 29884416)};
  unsigned short* xbb[2] = {(unsigned short*)(similar + 27787264),
                            (unsigned short*)(similar + 31981568)};
  // scratch in 'simil' region:
  unsigned short* hbufb = (unsigned short*)simil;                 // 67.1M ush
  unsigned short* wbuf = (unsigned short*)(simil + 33554432);
  const size_t WSZ = 559104;  // wqkv 44544 + wo 14848 + w1 262144 + w2 237568

  // d_ws layout for sim (bytes)
  unsigned char* ws = (unsigned char*)d_ws;
  unsigned short* feaT = (unsigned short*)ws;                   // 1,048,576 B
  unsigned short* simT = (unsigned short*)(ws + 1048576);       // 1,425,408 B
  float* fnb = (float*)(ws + 2473984);                          //    32,768 B
  float* snb = (float*)(ws + 2506752);                          //    44,544 B
  const bool ws_ok = ws_size >= 2551296;

  {
    ConvJobs J;
    int cum = 0;
    auto add = [&](int j, const float* s, unsigned short* dd, int R, int K,
                   int Kp, int mode) {
      J.src[j] = s; J.dst[j] = dd; J.K[j] = K; J.Kp[j] = Kp; J.mode[j] = mode;
      J.cum[j] = cum; cum += R * Kp;
    };
    add(0, x0, Ab, 32768, 116, 128, 0);
    for (int L = 0; L < 2; ++L) {
      unsigned short* wb = wbuf + L * WSZ;
      add(1 + L * 4, p[L * 12 + 0], wb + 0, 348, 116, 128, 0);
      add(2 + L * 4, p[L * 12 + 2], wb + 44544, 116, 116, 128, 1);  // wo spread
      add(3 + L * 4, p[L * 12 + 6], wb + 59392, 2048, 116, 128, 0);
      add(4 + L * 4, p[L * 12 + 8], wb + 321536, 116, 2048, 2048, 0);
    }
    J.cum[9] = cum;
    hipLaunchKernelGGL(convert_all_kernel, dim3(2048), dim3(256), 0, stream, J);
  }

  const unsigned short* Ain = Ab;
  const float* resin = x0;
  for (int L = 0; L < 2; ++L) {
    unsigned short* wb = wbuf + L * WSZ;
    const float* bqkv = p[L * 12 + 1];
    const float* bo = p[L * 12 + 3];
    const float* g1 = p[L * 12 + 4];
    const float* bn1 = p[L * 12 + 5];
    const float* b1 = p[L * 12 + 7];
    const float* b2 = p[L * 12 + 9];
    const float* g2 = p[L * 12 + 10];
    const float* bn2 = p[L * 12 + 11];

    // qkv -> head-major layout
    hipLaunchKernelGGL((mgemm_kernel<3>), dim3(256, 3), dim3(256), 0, stream,
                       Ain, wb + 0, bqkv, 348, 128, 0, qkvp);
    hipLaunchKernelGGL(attn_kernel, dim3(2048), dim3(64), 0, stream, qkvp,
                       obufb);
    // o-proj + res + LN (64-row tiles)
    hipLaunchKernelGGL(mgemm64_ln_kernel, dim3(512), dim3(256), 0, stream,
                       obufb, wb + 44544, bo, 128, xab[L], xa_f[L], resin, g1,
                       bn1);
    // FFN1
    hipLaunchKernelGGL((mgemm_kernel<1>), dim3(256, 16), dim3(256), 0, stream,
                       xab[L], wb + 59392, b1, 2048, 128, 2048, hbufb);
    // FFN2 + res + LN (64-row tiles)
    hipLaunchKernelGGL(mgemm64_ln_kernel, dim3(512), dim3(256), 0, stream,
                       hbufb, wb + 321536, b2, 2048, xbb[L], xb_f[L], xa_f[L],
                       g2, bn2);
    Ain = xbb[L];
    resin = xb_f[L];
  }

  hipLaunchKernelGGL(fc_kernel, dim3(4, 64), dim3(256), 0, stream, xb_f[1],
                     fc_w, fc_b, fea);
  if (ws_ok) {
    hipLaunchKernelGGL(sim_prep_kernel, dim3(180), dim3(256), 0, stream, fea,
                       simin, feaT, simT, fnb, snb);
    hipLaunchKernelGGL(sim_mfma2_kernel, dim3(116, 64), dim3(256), 0, stream,
                       feaT, simT, fnb, snb, simil, similar);
  } else {
    hipLaunchKernelGGL(sim_mfma_kernel, dim3(116, 64), dim3(256), 0, stream,
                       fea, simin, simil, similar);
  }
}

// Round 7
// 662.838 us; speedup vs baseline: 5.9984x; 1.1383x over previous
//
#include <hip/hip_runtime.h>
#include <hip/hip_bf16.h>

typedef __attribute__((ext_vector_type(8))) short short8v;
typedef __attribute__((ext_vector_type(4))) float floatx4;

__device__ __forceinline__ float bf2f(unsigned short u) {
  union { unsigned int i; float f; } c;
  c.i = ((unsigned int)u) << 16;
  return c.f;
}
__device__ __forceinline__ unsigned short f2bf(float f) {
  __hip_bfloat16 h = __float2bfloat16(f);
  return *reinterpret_cast<unsigned short*>(&h);
}

// ---------------------------------------------------------------------------
// Fused conversion: 9 jobs fp32 -> bf16.
// mode 0: [R x K] -> [R x Kp] zero-padded tail.
// mode 1: wo spread: src [116 x 116] (col e=h*29+d) -> dst [116 x 128]
//         (col h*32+d, d=29..31 zero).
// ---------------------------------------------------------------------------
struct ConvJobs {
  const float* src[9];
  unsigned short* dst[9];
  int K[9];
  int Kp[9];
  int mode[9];
  int cum[10];
};

__global__ __launch_bounds__(256) void convert_all_kernel(ConvJobs J) {
  const int total = J.cum[9];
  for (int idx = blockIdx.x * 256 + threadIdx.x; idx < total;
       idx += gridDim.x * 256) {
    int j = 0;
    while (idx >= J.cum[j + 1]) ++j;
    const int local = idx - J.cum[j];
    const int Kp = J.Kp[j];
    const int r = local / Kp, c = local - r * Kp;
    unsigned short v;
    if (J.mode[j] == 0) {
      v = (c < J.K[j]) ? f2bf(J.src[j][(size_t)r * J.K[j] + c])
                       : (unsigned short)0;
    } else {
      const int h = c >> 5, d = c & 31;
      v = (d < 29) ? f2bf(J.src[j][(size_t)r * 116 + h * 29 + d])
                   : (unsigned short)0;
    }
    J.dst[j][local] = v;
  }
}

// ---------------------------------------------------------------------------
// MFMA GEMM 128x128 tile.  MODE 3: qkv head-major output
//   qkvp[which][n][h][s][32], which=col/116, h=(col%116)/29, n=row&511,
//   s=row>>9.
// ---------------------------------------------------------------------------
template <int MODE>
__global__ __launch_bounds__(256) void mgemm_kernel(
    const unsigned short* __restrict__ A, const unsigned short* __restrict__ B,
    const float* __restrict__ bias, int N, int Kp, int ldout,
    unsigned short* __restrict__ Yb) {
  __shared__ __align__(16) unsigned short As[128][64];
  __shared__ __align__(16) unsigned short Bs[128][64];

  const int tid = threadIdx.x;
  const int M0 = blockIdx.x * 128;
  const int N0 = blockIdx.y * 128;
  const int wid = tid >> 6, lane = tid & 63;
  const int wr = wid >> 1, wc = wid & 1;
  const int lc = lane & 15, g = lane >> 4;
  const int srow = tid >> 1, shalf = tid & 1;
  const int sw = srow & 7;

  floatx4 acc[4][4] = {};

  const int nk = Kp >> 6;
  for (int kt = 0; kt < nk; ++kt) {
    const int k0 = kt << 6;
    {
      const uint4* p = reinterpret_cast<const uint4*>(
          A + (size_t)(M0 + srow) * Kp + k0 + shalf * 32);
      uint4 v0 = p[0], v1 = p[1], v2 = p[2], v3 = p[3];
      *reinterpret_cast<uint4*>(&As[srow][((((shalf << 2) | 0) ^ sw) << 3)]) = v0;
      *reinterpret_cast<uint4*>(&As[srow][((((shalf << 2) | 1) ^ sw) << 3)]) = v1;
      *reinterpret_cast<uint4*>(&As[srow][((((shalf << 2) | 2) ^ sw) << 3)]) = v2;
      *reinterpret_cast<uint4*>(&As[srow][((((shalf << 2) | 3) ^ sw) << 3)]) = v3;
    }
    {
      uint4 v0 = {0, 0, 0, 0}, v1 = v0, v2 = v0, v3 = v0;
      const int jr = N0 + srow;
      if (jr < N) {
        const uint4* p = reinterpret_cast<const uint4*>(
            B + (size_t)jr * Kp + k0 + shalf * 32);
        v0 = p[0]; v1 = p[1]; v2 = p[2]; v3 = p[3];
      }
      *reinterpret_cast<uint4*>(&Bs[srow][((((shalf << 2) | 0) ^ sw) << 3)]) = v0;
      *reinterpret_cast<uint4*>(&Bs[srow][((((shalf << 2) | 1) ^ sw) << 3)]) = v1;
      *reinterpret_cast<uint4*>(&Bs[srow][((((shalf << 2) | 2) ^ sw) << 3)]) = v2;
      *reinterpret_cast<uint4*>(&Bs[srow][((((shalf << 2) | 3) ^ sw) << 3)]) = v3;
    }
    __syncthreads();
#pragma unroll
    for (int ks = 0; ks < 2; ++ks) {
      short8v a[4], b[4];
#pragma unroll
      for (int m = 0; m < 4; ++m) {
        const int row = wr * 64 + m * 16 + lc;
        a[m] = *reinterpret_cast<const short8v*>(
            &As[row][((((ks << 2) | g) ^ (lc & 7)) << 3)]);
      }
#pragma unroll
      for (int n = 0; n < 4; ++n) {
        const int col = wc * 64 + n * 16 + lc;
        b[n] = *reinterpret_cast<const short8v*>(
            &Bs[col][((((ks << 2) | g) ^ (lc & 7)) << 3)]);
      }
#pragma unroll
      for (int m = 0; m < 4; ++m)
#pragma unroll
        for (int n = 0; n < 4; ++n)
          acc[m][n] = __builtin_amdgcn_mfma_f32_16x16x32_bf16(a[m], b[n],
                                                              acc[m][n], 0, 0, 0);
    }
    __syncthreads();
  }

#pragma unroll
  for (int m = 0; m < 4; ++m) {
#pragma unroll
    for (int r = 0; r < 4; ++r) {
      const int row = M0 + wr * 64 + m * 16 + g * 4 + r;
#pragma unroll
      for (int n = 0; n < 4; ++n) {
        const int col = N0 + wc * 64 + n * 16 + lc;
        if (col < N) {
          float v = acc[m][n][r] + bias[col];
          if (MODE == 1) v = fmaxf(v, 0.f);
          if constexpr (MODE == 3) {
            const int which = (col >= 232) ? 2 : (col >= 116 ? 1 : 0);
            const int cw = col - which * 116;
            const int h = (cw * 565) >> 14;
            const int d = cw - h * 29;
            const int nn2 = row & 511, ss = row >> 9;
            Yb[(size_t)which * 4194304 +
               ((((size_t)nn2 * 4 + h) * 64 + ss) << 5) + d] = f2bf(v);
          } else {
            Yb[(size_t)row * ldout + col] = f2bf(v);
          }
        }
      }
    }
  }
}

// ---------------------------------------------------------------------------
// 64-row-tile GEMM + residual + LayerNorm (N=116).  Used for o-proj (K=128).
// ---------------------------------------------------------------------------
__global__ __launch_bounds__(256) void mgemm64_ln_kernel(
    const unsigned short* __restrict__ A, const unsigned short* __restrict__ B,
    const float* __restrict__ bias, int Kp, unsigned short* __restrict__ Yb,
    float* __restrict__ Yf, const float* __restrict__ res,
    const float* __restrict__ gw, const float* __restrict__ bw) {
  __shared__ __align__(16) unsigned short As[64][64];
  __shared__ __align__(16) unsigned short Bs[128][64];
  __shared__ float sum1[2][64];
  __shared__ float sum2[2][64];

  const int tid = threadIdx.x;
  const int M0 = blockIdx.x * 64;
  const int wid = tid >> 6, lane = tid & 63;
  const int wr = wid >> 1, wc = wid & 1;
  const int lc = lane & 15, g = lane >> 4;
  const int arow = tid >> 2, aq = tid & 3;
  const int brow = tid >> 1, bhalf = tid & 1;

  floatx4 acc[2][4] = {};

  const int nk = Kp >> 6;
  for (int kt = 0; kt < nk; ++kt) {
    const int k0 = kt << 6;
    {
      const uint4* p = reinterpret_cast<const uint4*>(
          A + (size_t)(M0 + arow) * Kp + k0 + aq * 16);
      uint4 v0 = p[0], v1 = p[1];
      const int swa = arow & 7;
      *reinterpret_cast<uint4*>(&As[arow][(((aq * 2) ^ swa) << 3)]) = v0;
      *reinterpret_cast<uint4*>(&As[arow][(((aq * 2 + 1) ^ swa) << 3)]) = v1;
    }
    {
      uint4 v0 = {0, 0, 0, 0}, v1 = v0, v2 = v0, v3 = v0;
      if (brow < 116) {
        const uint4* p = reinterpret_cast<const uint4*>(
            B + (size_t)brow * Kp + k0 + bhalf * 32);
        v0 = p[0]; v1 = p[1]; v2 = p[2]; v3 = p[3];
      }
      const int sw = brow & 7;
      *reinterpret_cast<uint4*>(&Bs[brow][((((bhalf << 2) | 0) ^ sw) << 3)]) = v0;
      *reinterpret_cast<uint4*>(&Bs[brow][((((bhalf << 2) | 1) ^ sw) << 3)]) = v1;
      *reinterpret_cast<uint4*>(&Bs[brow][((((bhalf << 2) | 2) ^ sw) << 3)]) = v2;
      *reinterpret_cast<uint4*>(&Bs[brow][((((bhalf << 2) | 3) ^ sw) << 3)]) = v3;
    }
    __syncthreads();
#pragma unroll
    for (int ks = 0; ks < 2; ++ks) {
      short8v a[2], b[4];
#pragma unroll
      for (int m = 0; m < 2; ++m) {
        const int row = wr * 32 + m * 16 + lc;
        a[m] = *reinterpret_cast<const short8v*>(
            &As[row][((((ks << 2) | g) ^ (row & 7)) << 3)]);
      }
#pragma unroll
      for (int n = 0; n < 4; ++n) {
        const int col = wc * 64 + n * 16 + lc;
        b[n] = *reinterpret_cast<const short8v*>(
            &Bs[col][((((ks << 2) | g) ^ (col & 7)) << 3)]);
      }
#pragma unroll
      for (int m = 0; m < 2; ++m)
#pragma unroll
        for (int n = 0; n < 4; ++n)
          acc[m][n] = __builtin_amdgcn_mfma_f32_16x16x32_bf16(a[m], b[n],
                                                              acc[m][n], 0, 0, 0);
    }
    __syncthreads();
  }

  float s1l[2][4], s2l[2][4];
#pragma unroll
  for (int m = 0; m < 2; ++m) {
#pragma unroll
    for (int r = 0; r < 4; ++r) {
      const int row = M0 + wr * 32 + m * 16 + g * 4 + r;
      float s = 0.f, s2 = 0.f;
#pragma unroll
      for (int n = 0; n < 4; ++n) {
        const int col = wc * 64 + n * 16 + lc;
        float v = 0.f;
        if (col < 116)
          v = acc[m][n][r] + bias[col] + res[(size_t)row * 116 + col];
        acc[m][n][r] = v;
        s += v;
        s2 = fmaf(v, v, s2);
      }
#pragma unroll
      for (int st = 1; st < 16; st <<= 1) {
        s += __shfl_xor(s, st, 16);
        s2 += __shfl_xor(s2, st, 16);
      }
      s1l[m][r] = s;
      s2l[m][r] = s2;
    }
  }
  if (lc == 0) {
#pragma unroll
    for (int m = 0; m < 2; ++m)
#pragma unroll
      for (int r = 0; r < 4; ++r) {
        const int lrow = wr * 32 + m * 16 + g * 4 + r;
        sum1[wc][lrow] = s1l[m][r];
        sum2[wc][lrow] = s2l[m][r];
      }
  }
  __syncthreads();
#pragma unroll
  for (int m = 0; m < 2; ++m) {
#pragma unroll
    for (int r = 0; r < 4; ++r) {
      const int lrow = wr * 32 + m * 16 + g * 4 + r;
      const int row = M0 + lrow;
      const float st = sum1[0][lrow] + sum1[1][lrow];
      const float s2t = sum2[0][lrow] + sum2[1][lrow];
      const float mean = st * (1.f / 116.f);
      const float var = s2t * (1.f / 116.f) - mean * mean;
      const float rstd = 1.f / sqrtf(var + 1e-5f);
#pragma unroll
      for (int n = 0; n < 4; ++n) {
        const int col = wc * 64 + n * 16 + lc;
        if (col < 116) {
          const float y = (acc[m][n][r] - mean) * rstd * gw[col] + bw[col];
          Yf[(size_t)row * 116 + col] = y;
          Yb[(size_t)row * 128 + col] = f2bf(y);
        } else {
          Yb[(size_t)row * 128 + col] = 0;
        }
      }
    }
  }
}

// ---------------------------------------------------------------------------
// Fused FFN: out = LayerNorm(res + relu(Xa @ W1^T + b1) @ W2^T + b2)
// Block = 64 tokens (grid 512).  DFF looped in 32 chunks of 64; hidden tile
// lives only in LDS (never touches HBM).
// ---------------------------------------------------------------------------
__global__ __launch_bounds__(256) void ffn_fused_kernel(
    const unsigned short* __restrict__ Xa,  // bf16 [32768][128]
    const unsigned short* __restrict__ W1,  // bf16 [2048][128]
    const float* __restrict__ b1,
    const unsigned short* __restrict__ W2,  // bf16 [116][2048]
    const float* __restrict__ b2, const float* __restrict__ res,
    const float* __restrict__ gw, const float* __restrict__ bw,
    unsigned short* __restrict__ Yb,  // bf16 [32768][128]
    float* __restrict__ Yf) {         // fp32 [32768][116]
  __shared__ __align__(16) unsigned short Xs[64][128];
  __shared__ __align__(16) unsigned short W1c[64][128];
  __shared__ __align__(16) unsigned short W2c[128][64];
  __shared__ __align__(16) unsigned short Hs[64][64];
  __shared__ float sum1[2][64];
  __shared__ float sum2[2][64];

  const int tid = threadIdx.x;
  const int M0 = blockIdx.x * 64;
  const int wid = tid >> 6, lane = tid & 63;
  const int wr = wid >> 1, wc = wid & 1;
  const int lc = lane & 15, g = lane >> 4;
  const int arow = tid >> 2, aq = tid & 3;       // A-style staging (64x128)
  const int brow = tid >> 1, bh = tid & 1;       // B-style staging (128x64)

  // stage Xa tile once (swizzled 16B chunks: swz = (cj&8) | ((cj^row)&7))
  {
    const uint4* p = reinterpret_cast<const uint4*>(
        Xa + (size_t)(M0 + arow) * 128 + aq * 32);
#pragma unroll
    for (int q = 0; q < 4; ++q) {
      const int cj = aq * 4 + q;
      const int swz = (cj & 8) | ((cj ^ arow) & 7);
      *reinterpret_cast<uint4*>(&Xs[arow][swz * 8]) = p[q];
    }
  }

  floatx4 oacc[2][4] = {};

  for (int kc = 0; kc < 32; ++kc) {
    // stage W1 chunk (rows = dff kc*64..+64, all 128 K cols)
    {
      const uint4* p = reinterpret_cast<const uint4*>(
          W1 + (size_t)(kc * 64 + arow) * 128 + aq * 32);
#pragma unroll
      for (int q = 0; q < 4; ++q) {
        const int cj = aq * 4 + q;
        const int swz = (cj & 8) | ((cj ^ arow) & 7);
        *reinterpret_cast<uint4*>(&W1c[arow][swz * 8]) = p[q];
      }
    }
    // stage W2 chunk (rows = e 0..115 pad 128, cols = dff kc*64..+64)
    {
      uint4 v[4] = {};
      if (brow < 116) {
        const uint4* p = reinterpret_cast<const uint4*>(
            W2 + (size_t)brow * 2048 + kc * 64 + bh * 32);
        v[0] = p[0]; v[1] = p[1]; v[2] = p[2]; v[3] = p[3];
      }
#pragma unroll
      for (int q = 0; q < 4; ++q) {
        const int cj = bh * 4 + q;
        const int swz = (cj ^ brow) & 7;
        *reinterpret_cast<uint4*>(&W2c[brow][swz * 8]) = v[q];
      }
    }
    __syncthreads();

    // h = Xs @ W1c^T : wave tile 32x32, K=128 (4 ks)
    floatx4 hacc[2][2] = {};
#pragma unroll
    for (int ks = 0; ks < 4; ++ks) {
      short8v av[2], bv[2];
#pragma unroll
      for (int m = 0; m < 2; ++m) {
        const int row = wr * 32 + m * 16 + lc;
        const int cj = ks * 4 + g;
        const int swz = (cj & 8) | ((cj ^ row) & 7);
        av[m] = *reinterpret_cast<const short8v*>(&Xs[row][swz * 8]);
      }
#pragma unroll
      for (int n = 0; n < 2; ++n) {
        const int row = wc * 32 + n * 16 + lc;
        const int cj = ks * 4 + g;
        const int swz = (cj & 8) | ((cj ^ row) & 7);
        bv[n] = *reinterpret_cast<const short8v*>(&W1c[row][swz * 8]);
      }
#pragma unroll
      for (int m = 0; m < 2; ++m)
#pragma unroll
        for (int n = 0; n < 2; ++n)
          hacc[m][n] = __builtin_amdgcn_mfma_f32_16x16x32_bf16(av[m], bv[n],
                                                               hacc[m][n], 0, 0, 0);
    }
    // relu + b1 -> bf16 -> Hs (swizzled 8-chunk)
#pragma unroll
    for (int n = 0; n < 2; ++n) {
      const int dff = wc * 32 + n * 16 + lc;
      const float bb = b1[kc * 64 + dff];
      const int cj = dff >> 3;
      const int dlo = dff & 7;
#pragma unroll
      for (int m = 0; m < 2; ++m) {
#pragma unroll
        for (int r = 0; r < 4; ++r) {
          const int tok = wr * 32 + m * 16 + g * 4 + r;
          const float hv = fmaxf(hacc[m][n][r] + bb, 0.f);
          Hs[tok][(((cj ^ tok) & 7) << 3) | dlo] = f2bf(hv);
        }
      }
    }
    __syncthreads();

    // oacc += Hs @ W2c^T : wave tile 32(tok) x 64(e), K=64 (2 ks)
#pragma unroll
    for (int ks = 0; ks < 2; ++ks) {
      short8v av[2], bv[4];
#pragma unroll
      for (int m = 0; m < 2; ++m) {
        const int row = wr * 32 + m * 16 + lc;
        const int cj = ks * 4 + g;
        av[m] = *reinterpret_cast<const short8v*>(
            &Hs[row][(((cj ^ row) & 7) << 3)]);
      }
#pragma unroll
      for (int n = 0; n < 4; ++n) {
        const int col = wc * 64 + n * 16 + lc;
        const int cj = ks * 4 + g;
        bv[n] = *reinterpret_cast<const short8v*>(
            &W2c[col][(((cj ^ col) & 7) << 3)]);
      }
#pragma unroll
      for (int m = 0; m < 2; ++m)
#pragma unroll
        for (int n = 0; n < 4; ++n)
          oacc[m][n] = __builtin_amdgcn_mfma_f32_16x16x32_bf16(av[m], bv[n],
                                                               oacc[m][n], 0, 0, 0);
    }
    __syncthreads();
  }

  // residual + LayerNorm epilogue (same as mgemm64_ln)
  float s1l[2][4], s2l[2][4];
#pragma unroll
  for (int m = 0; m < 2; ++m) {
#pragma unroll
    for (int r = 0; r < 4; ++r) {
      const int row = M0 + wr * 32 + m * 16 + g * 4 + r;
      float s = 0.f, s2 = 0.f;
#pragma unroll
      for (int n = 0; n < 4; ++n) {
        const int col = wc * 64 + n * 16 + lc;
        float v = 0.f;
        if (col < 116)
          v = oacc[m][n][r] + b2[col] + res[(size_t)row * 116 + col];
        oacc[m][n][r] = v;
        s += v;
        s2 = fmaf(v, v, s2);
      }
#pragma unroll
      for (int st = 1; st < 16; st <<= 1) {
        s += __shfl_xor(s, st, 16);
        s2 += __shfl_xor(s2, st, 16);
      }
      s1l[m][r] = s;
      s2l[m][r] = s2;
    }
  }
  if (lc == 0) {
#pragma unroll
    for (int m = 0; m < 2; ++m)
#pragma unroll
      for (int r = 0; r < 4; ++r) {
        const int lrow = wr * 32 + m * 16 + g * 4 + r;
        sum1[wc][lrow] = s1l[m][r];
        sum2[wc][lrow] = s2l[m][r];
      }
  }
  __syncthreads();
#pragma unroll
  for (int m = 0; m < 2; ++m) {
#pragma unroll
    for (int r = 0; r < 4; ++r) {
      const int lrow = wr * 32 + m * 16 + g * 4 + r;
      const int row = M0 + lrow;
      const float st = sum1[0][lrow] + sum1[1][lrow];
      const float s2t = sum2[0][lrow] + sum2[1][lrow];
      const float mean = st * (1.f / 116.f);
      const float var = s2t * (1.f / 116.f) - mean * mean;
      const float rstd = 1.f / sqrtf(var + 1e-5f);
#pragma unroll
      for (int n = 0; n < 4; ++n) {
        const int col = wc * 64 + n * 16 + lc;
        if (col < 116) {
          const float y = (oacc[m][n][r] - mean) * rstd * gw[col] + bw[col];
          Yf[(size_t)row * 116 + col] = y;
          Yb[(size_t)row * 128 + col] = f2bf(y);
        } else {
          Yb[(size_t)row * 128 + col] = 0;
        }
      }
    }
  }
}

// ---------------------------------------------------------------------------
// Attention, head-major coalesced I/O.  Block (n,h), 64 threads (lane = s).
// ---------------------------------------------------------------------------
__global__ __launch_bounds__(64) void attn_kernel(
    const unsigned short* __restrict__ qkvp, unsigned short* __restrict__ obuf) {
  const int h = blockIdx.x & 3;
  const int n = blockIdx.x >> 2;
  const int s = threadIdx.x;
  __shared__ float ks[64][36];
  __shared__ float vs[64][36];

  const size_t rb = (((size_t)n * 4 + h) * 64 + s) * 32;
  const uint4* qp = reinterpret_cast<const uint4*>(qkvp + rb);
  const uint4* kp = reinterpret_cast<const uint4*>(qkvp + 4194304 + rb);
  const uint4* vp = reinterpret_cast<const uint4*>(qkvp + 8388608 + rb);
  uint4 qv[4], kv4[4], vv4[4];
#pragma unroll
  for (int i = 0; i < 4; ++i) {
    qv[i] = qp[i];
    kv4[i] = kp[i];
    vv4[i] = vp[i];
  }
  float q[32], kf[32], vf[32];
#pragma unroll
  for (int i = 0; i < 4; ++i) {
    const unsigned* wq = reinterpret_cast<const unsigned*>(&qv[i]);
    const unsigned* wk = reinterpret_cast<const unsigned*>(&kv4[i]);
    const unsigned* wv = reinterpret_cast<const unsigned*>(&vv4[i]);
#pragma unroll
    for (int j = 0; j < 4; ++j) {
      union { unsigned u; float f; } lo, hi;
      const int d0 = i * 8 + 2 * j;
      lo.u = wq[j] << 16; hi.u = wq[j] & 0xffff0000u;
      q[d0] = lo.f; q[d0 + 1] = hi.f;
      lo.u = wk[j] << 16; hi.u = wk[j] & 0xffff0000u;
      kf[d0] = (d0 < 29) ? lo.f : 0.f;
      kf[d0 + 1] = (d0 + 1 < 29) ? hi.f : 0.f;
      lo.u = wv[j] << 16; hi.u = wv[j] & 0xffff0000u;
      vf[d0] = (d0 < 29) ? lo.f : 0.f;
      vf[d0 + 1] = (d0 + 1 < 29) ? hi.f : 0.f;
    }
  }
  q[29] = q[30] = q[31] = 0.f;
#pragma unroll
  for (int c = 0; c < 8; ++c) {
    *reinterpret_cast<float4*>(&ks[s][c * 4]) =
        make_float4(kf[4 * c], kf[4 * c + 1], kf[4 * c + 2], kf[4 * c + 3]);
    *reinterpret_cast<float4*>(&vs[s][c * 4]) =
        make_float4(vf[4 * c], vf[4 * c + 1], vf[4 * c + 2], vf[4 * c + 3]);
  }
  __syncthreads();

  const float scale = 0.18569533817705186f;  // 1/sqrt(29)
  float sc[64];
#pragma unroll 4
  for (int t = 0; t < 64; ++t) {
    const float4* kr = reinterpret_cast<const float4*>(&ks[t][0]);
    float a = 0.f;
#pragma unroll
    for (int c = 0; c < 8; ++c) {
      const float4 kc = kr[c];
      a = fmaf(q[4 * c], kc.x, a);
      a = fmaf(q[4 * c + 1], kc.y, a);
      a = fmaf(q[4 * c + 2], kc.z, a);
      a = fmaf(q[4 * c + 3], kc.w, a);
    }
    sc[t] = a * scale;
  }
  float m = sc[0];
#pragma unroll
  for (int t = 1; t < 64; ++t) m = fmaxf(m, sc[t]);
  float sum = 0.f;
#pragma unroll
  for (int t = 0; t < 64; ++t) {
    sc[t] = __expf(sc[t] - m);
    sum += sc[t];
  }
  const float inv = 1.f / sum;
  float o[32] = {};
#pragma unroll 4
  for (int t = 0; t < 64; ++t) {
    const float p = sc[t];
    const float4* vr = reinterpret_cast<const float4*>(&vs[t][0]);
#pragma unroll
    for (int c = 0; c < 8; ++c) {
      const float4 vc = vr[c];
      o[4 * c] = fmaf(p, vc.x, o[4 * c]);
      o[4 * c + 1] = fmaf(p, vc.y, o[4 * c + 1]);
      o[4 * c + 2] = fmaf(p, vc.z, o[4 * c + 2]);
      o[4 * c + 3] = fmaf(p, vc.w, o[4 * c + 3]);
    }
  }
  unsigned short ow[32];
#pragma unroll
  for (int i = 0; i < 32; ++i) ow[i] = f2bf(o[i] * inv);
  uint4* od =
      reinterpret_cast<uint4*>(obuf + ((size_t)s * 512 + n) * 128 + h * 32);
  const uint4* ows = reinterpret_cast<const uint4*>(ow);
#pragma unroll
  for (int i = 0; i < 4; ++i) od[i] = ows[i];
}

// ---------------------------------------------------------------------------
// fc: feas[b,h,e] = sum_t x4[b,t,e] * fc_w[h,t] + fc_b[h]   (fp32)
// ---------------------------------------------------------------------------
__global__ __launch_bounds__(256) void fc_kernel(const float* __restrict__ X4,
                                                 const float* __restrict__ fw,
                                                 const float* __restrict__ fb,
                                                 float* __restrict__ fea) {
  const int eg = blockIdx.x;  // 0..3
  const int b = blockIdx.y;   // 0..63
  const int e0 = eg * 29;
  __shared__ float Os[64][30];
  __shared__ float Wf[64][65];
  const int tid = threadIdx.x;
  const int h = tid & 63, jg = tid >> 6;
  float acc[8] = {};

  for (int tc = 0; tc < 8; ++tc) {
    for (int idx = tid; idx < 64 * 29; idx += 256) {
      int tt = idx / 29;
      int ee = idx - tt * 29;
      Os[tt][ee] = X4[((size_t)b * 512 + tc * 64 + tt) * 116 + e0 + ee];
    }
    for (int idx = tid; idx < 64 * 64; idx += 256) {
      int hh = idx >> 6, t2 = idx & 63;
      Wf[hh][t2] = fw[(size_t)hh * 512 + tc * 64 + t2];
    }
    __syncthreads();
#pragma unroll 4
    for (int t = 0; t < 64; ++t) {
      const float w = Wf[h][t];
#pragma unroll
      for (int m = 0; m < 8; ++m) {
        const int el = jg + 4 * m;
        if (el < 29) acc[m] = fmaf(Os[t][el], w, acc[m]);
      }
    }
    __syncthreads();
  }
  const float bb = fb[h];
#pragma unroll
  for (int m = 0; m < 8; ++m) {
    const int el = jg + 4 * m;
    if (el < 29) fea[((size_t)b * 64 + h) * 116 + e0 + el] = acc[m] + bb;
  }
}

// ---------------------------------------------------------------------------
// sim prep: feaT[b][d(128)][h(64)] bf16, fn[b][128]; simT[a][c(96)][h] bf16,
// sn[a][96].
// ---------------------------------------------------------------------------
__global__ __launch_bounds__(256) void sim_prep_kernel(
    const float* __restrict__ fea, const float* __restrict__ simin,
    unsigned short* __restrict__ feaT, unsigned short* __restrict__ simT,
    float* __restrict__ fn, float* __restrict__ sn) {
  __shared__ float L[64][121];
  const int blk = blockIdx.x;
  const int tid = threadIdx.x;
  if (blk < 64) {
    const int b = blk;
    for (int idx = tid; idx < 64 * 116; idx += 256) {
      const int h = idx / 116, d = idx - h * 116;
      L[h][d] = bf2f(f2bf(fea[((size_t)b * 64 + h) * 116 + d]));
    }
    __syncthreads();
    for (int idx = tid; idx < 128 * 64; idx += 256) {
      const int d = idx >> 6, h = idx & 63;
      feaT[((size_t)b * 128 + d) * 64 + h] = (d < 116) ? f2bf(L[h][d]) : 0;
    }
    if (tid < 116) {
      float s = 0.f;
#pragma unroll 8
      for (int h = 0; h < 64; ++h) {
        const float t = L[h][tid];
        s = fmaf(t, t, s);
      }
      fn[b * 128 + tid] = sqrtf(s);
    }
  } else {
    const int a = blk - 64;
    for (int idx = tid; idx < 64 * 90; idx += 256) {
      const int h = idx / 90, c = idx - h * 90;
      L[h][c] = bf2f(f2bf(simin[((size_t)a * 64 + h) * 90 + c]));
    }
    __syncthreads();
    for (int idx = tid; idx < 96 * 64; idx += 256) {
      const int c = idx >> 6, h = idx & 63;
      simT[((size_t)a * 96 + c) * 64 + h] = (c < 90) ? f2bf(L[h][c]) : 0;
    }
    if (tid < 90) {
      float s = 0.f;
#pragma unroll 8
      for (int h = 0; h < 64; ++h) {
        const float t = L[h][tid];
        s = fmaf(t, t, s);
      }
      sn[a * 96 + tid] = sqrtf(s);
    }
  }
}

// ---------------------------------------------------------------------------
// Similarity v2: staged from pre-transposed feaT/simT + precomputed norms.
// ---------------------------------------------------------------------------
__global__ __launch_bounds__(256) void sim_mfma2_kernel(
    const unsigned short* __restrict__ feaT, const unsigned short* __restrict__ simT,
    const float* __restrict__ fn, const float* __restrict__ sn,
    float* __restrict__ simil, float* __restrict__ similar) {
  const int a = blockIdx.x;  // 0..115
  const int b = blockIdx.y;  // 0..63
  __shared__ __align__(16) unsigned char shmem[41760];
  __shared__ float fnrow[116];
  __shared__ float snrow[90];
  __shared__ float wred[4];
  const int tid = threadIdx.x;

  unsigned short (*Ft)[64] = reinterpret_cast<unsigned short(*)[64]>(shmem);
  unsigned short (*St)[64] =
      reinterpret_cast<unsigned short(*)[64]>(shmem + 16384);
  float* Rs = reinterpret_cast<float*>(shmem);

  const int srow = tid >> 1, shalf = tid & 1;
  const int sw = srow & 7;
  {
    const uint4* p = reinterpret_cast<const uint4*>(
        feaT + ((size_t)b * 128 + srow) * 64 + shalf * 32);
    uint4 v0 = p[0], v1 = p[1], v2 = p[2], v3 = p[3];
    *reinterpret_cast<uint4*>(&Ft[srow][((((shalf << 2) | 0) ^ sw) << 3)]) = v0;
    *reinterpret_cast<uint4*>(&Ft[srow][((((shalf << 2) | 1) ^ sw) << 3)]) = v1;
    *reinterpret_cast<uint4*>(&Ft[srow][((((shalf << 2) | 2) ^ sw) << 3)]) = v2;
    *reinterpret_cast<uint4*>(&Ft[srow][((((shalf << 2) | 3) ^ sw) << 3)]) = v3;
  }
  if (srow < 96) {
    const uint4* p = reinterpret_cast<const uint4*>(
        simT + ((size_t)a * 96 + srow) * 64 + shalf * 32);
    uint4 v0 = p[0], v1 = p[1], v2 = p[2], v3 = p[3];
    *reinterpret_cast<uint4*>(&St[srow][((((shalf << 2) | 0) ^ sw) << 3)]) = v0;
    *reinterpret_cast<uint4*>(&St[srow][((((shalf << 2) | 1) ^ sw) << 3)]) = v1;
    *reinterpret_cast<uint4*>(&St[srow][((((shalf << 2) | 2) ^ sw) << 3)]) = v2;
    *reinterpret_cast<uint4*>(&St[srow][((((shalf << 2) | 3) ^ sw) << 3)]) = v3;
  }
  if (tid < 116) fnrow[tid] = fn[b * 128 + tid];
  else if (tid >= 128 && tid < 218) snrow[tid - 128] = sn[a * 96 + tid - 128];
  __syncthreads();

  const int wid = tid >> 6, lane = tid & 63;
  const int wr = wid >> 1, wc = wid & 1;
  const int lc = lane & 15, g = lane >> 4;

  floatx4 acc[4][3] = {};
#pragma unroll
  for (int ks = 0; ks < 2; ++ks) {
    short8v av[4], bv[3];
#pragma unroll
    for (int m = 0; m < 4; ++m) {
      const int row = wr * 64 + m * 16 + lc;
      av[m] = *reinterpret_cast<const short8v*>(
          &Ft[row][((((ks << 2) | g) ^ (lc & 7)) << 3)]);
    }
#pragma unroll
    for (int n = 0; n < 3; ++n) {
      const int col = wc * 48 + n * 16 + lc;
      bv[n] = *reinterpret_cast<const short8v*>(
          &St[col][((((ks << 2) | g) ^ (lc & 7)) << 3)]);
    }
#pragma unroll
    for (int m = 0; m < 4; ++m)
#pragma unroll
      for (int n = 0; n < 3; ++n)
        acc[m][n] = __builtin_amdgcn_mfma_f32_16x16x32_bf16(av[m], bv[n],
                                                            acc[m][n], 0, 0, 0);
  }
  __syncthreads();  // Ft/St dead; reuse as Rs

  float ss = 0.f;
#pragma unroll
  for (int m = 0; m < 4; ++m) {
#pragma unroll
    for (int r = 0; r < 4; ++r) {
      const int d = wr * 64 + m * 16 + g * 4 + r;
      if (d < 116) {
        const float fnv = fnrow[d];
#pragma unroll
        for (int n = 0; n < 3; ++n) {
          const int c = wc * 48 + n * 16 + lc;
          if (c < 90) {
            const float denom = fmaxf(fnv * snrow[c], 1e-8f);
            float rcp = __builtin_amdgcn_rcpf(denom);
            rcp = rcp * (2.0f - denom * rcp);
            const float v = acc[m][n][r] * rcp;
            ss = fmaf(v, v, ss);
            Rs[d * 90 + c] = v;
          }
        }
      }
    }
  }
#pragma unroll
  for (int st = 1; st <= 32; st <<= 1) ss += __shfl_xor(ss, st, 64);
  if (lane == 0) wred[wid] = ss;
  __syncthreads();
  const float tot = wred[0] + wred[1] + wred[2] + wred[3];
  const float inv = 1.f / fmaxf(sqrtf(tot), 1e-12f);

  const size_t rowbase = ((size_t)b * 116 + a) * (116 * 90);
  float4* so = reinterpret_cast<float4*>(simil + rowbase);
  float4* sr = reinterpret_cast<float4*>(similar + rowbase);
  const float4* rs4 = reinterpret_cast<const float4*>(Rs);
  for (int i = tid; i < 2610; i += 256) {
    float4 v = rs4[i];
    so[i] = v;
    float4 w;
    w.x = v.x * inv; w.y = v.y * inv; w.z = v.z * inv; w.w = v.w * inv;
    sr[i] = w;
  }
}

// ---------------------------------------------------------------------------
// Fallback similarity (self-contained) if d_ws is too small.
// ---------------------------------------------------------------------------
__global__ __launch_bounds__(256) void sim_mfma_kernel(
    const float* __restrict__ fea, const float* __restrict__ simin,
    float* __restrict__ simil, float* __restrict__ similar) {
  const int a = blockIdx.x;
  const int b = blockIdx.y;
  __shared__ __align__(16) unsigned char shmem[41760];
  __shared__ float fnrow[116];
  __shared__ float snrow[90];
  __shared__ float wred[4];
  const int tid = threadIdx.x;

  unsigned short (*Ft)[64] = reinterpret_cast<unsigned short(*)[64]>(shmem);
  unsigned short (*St)[64] =
      reinterpret_cast<unsigned short(*)[64]>(shmem + 16384);
  float* Rs = reinterpret_cast<float*>(shmem);

  for (int idx = tid; idx < 64 * 116; idx += 256) {
    const int h = idx / 116, d = idx - h * 116;
    Ft[d][(((h >> 3) ^ (d & 7)) << 3) | (h & 7)] =
        f2bf(fea[((size_t)b * 64 + h) * 116 + d]);
  }
  for (int idx = tid; idx < 12 * 64; idx += 256) {
    const int d = 116 + (idx >> 6), h = idx & 63;
    Ft[d][(((h >> 3) ^ (d & 7)) << 3) | (h & 7)] = 0;
  }
  for (int idx = tid; idx < 64 * 90; idx += 256) {
    const int h = idx / 90, c = idx - h * 90;
    St[c][(((h >> 3) ^ (c & 7)) << 3) | (h & 7)] =
        f2bf(simin[((size_t)a * 64 + h) * 90 + c]);
  }
  for (int idx = tid; idx < 6 * 64; idx += 256) {
    const int c = 90 + (idx >> 6), h = idx & 63;
    St[c][(((h >> 3) ^ (c & 7)) << 3) | (h & 7)] = 0;
  }
  __syncthreads();

  if (tid < 116) {
    float s = 0.f;
#pragma unroll 8
    for (int h = 0; h < 64; ++h) {
      const float t = bf2f(Ft[tid][(((h >> 3) ^ (tid & 7)) << 3) | (h & 7)]);
      s = fmaf(t, t, s);
    }
    fnrow[tid] = sqrtf(s);
  } else if (tid >= 128 && tid < 218) {
    const int c = tid - 128;
    float s = 0.f;
#pragma unroll 8
    for (int h = 0; h < 64; ++h) {
      const float t = bf2f(St[c][(((h >> 3) ^ (c & 7)) << 3) | (h & 7)]);
      s = fmaf(t, t, s);
    }
    snrow[c] = sqrtf(s);
  }
  __syncthreads();

  const int wid = tid >> 6, lane = tid & 63;
  const int wr = wid >> 1, wc = wid & 1;
  const int lc = lane & 15, g = lane >> 4;

  floatx4 acc[4][3] = {};
#pragma unroll
  for (int ks = 0; ks < 2; ++ks) {
    short8v av[4], bv[3];
#pragma unroll
    for (int m = 0; m < 4; ++m) {
      const int row = wr * 64 + m * 16 + lc;
      av[m] = *reinterpret_cast<const short8v*>(
          &Ft[row][((((ks << 2) | g) ^ (lc & 7)) << 3)]);
    }
#pragma unroll
    for (int n = 0; n < 3; ++n) {
      const int col = wc * 48 + n * 16 + lc;
      bv[n] = *reinterpret_cast<const short8v*>(
          &St[col][((((ks << 2) | g) ^ (lc & 7)) << 3)]);
    }
#pragma unroll
    for (int m = 0; m < 4; ++m)
#pragma unroll
      for (int n = 0; n < 3; ++n)
        acc[m][n] = __builtin_amdgcn_mfma_f32_16x16x32_bf16(av[m], bv[n],
                                                            acc[m][n], 0, 0, 0);
  }
  __syncthreads();

  float ss = 0.f;
#pragma unroll
  for (int m = 0; m < 4; ++m) {
#pragma unroll
    for (int r = 0; r < 4; ++r) {
      const int d = wr * 64 + m * 16 + g * 4 + r;
      if (d < 116) {
        const float fnv = fnrow[d];
#pragma unroll
        for (int n = 0; n < 3; ++n) {
          const int c = wc * 48 + n * 16 + lc;
          if (c < 90) {
            const float denom = fmaxf(fnv * snrow[c], 1e-8f);
            float rcp = __builtin_amdgcn_rcpf(denom);
            rcp = rcp * (2.0f - denom * rcp);
            const float v = acc[m][n][r] * rcp;
            ss = fmaf(v, v, ss);
            Rs[d * 90 + c] = v;
          }
        }
      }
    }
  }
#pragma unroll
  for (int st = 1; st <= 32; st <<= 1) ss += __shfl_xor(ss, st, 64);
  if (lane == 0) wred[wid] = ss;
  __syncthreads();
  const float tot = wred[0] + wred[1] + wred[2] + wred[3];
  const float inv = 1.f / fmaxf(sqrtf(tot), 1e-12f);

  const size_t rowbase = ((size_t)b * 116 + a) * (116 * 90);
  float4* so = reinterpret_cast<float4*>(simil + rowbase);
  float4* sr = reinterpret_cast<float4*>(similar + rowbase);
  const float4* rs4 = reinterpret_cast<const float4*>(Rs);
  for (int i = tid; i < 2610; i += 256) {
    float4 v = rs4[i];
    so[i] = v;
    float4 w;
    w.x = v.x * inv; w.y = v.y * inv; w.z = v.z * inv; w.w = v.w * inv;
    sr[i] = w;
  }
}

// ---------------------------------------------------------------------------
extern "C" void kernel_launch(void* const* d_in, const int* in_sizes, int n_in,
                              void* d_out, int out_size, void* d_ws,
                              size_t ws_size, hipStream_t stream) {
  const float* x0 = (const float*)d_in[0];
  const float* simin = (const float*)d_in[1];
  const float* p[24];
  for (int i = 0; i < 24; ++i) p[i] = (const float*)d_in[2 + i];
  const float* fc_w = (const float*)d_in[26];
  const float* fc_b = (const float*)d_in[27];

  float* out = (float*)d_out;
  float* fea = out;
  float* simil = out + 475136;       // 77,506,560 floats
  float* similar = out + 77981696;   // 475136 + 77506560

  // scratch in 'similar' region (all dead before sim writes it):
  float* xa_f[2] = {similar + 0, similar + 7602176};
  float* xb_f[2] = {similar + 3801088, similar + 11403264};
  unsigned short* obufb = (unsigned short*)(similar + 15204352);  // 4.19M ush
  unsigned short* qkvp = (unsigned short*)(similar + 17301504);   // 12.58M ush
  unsigned short* Ab = (unsigned short*)(similar + 23592960);     // 4.19M ush
  unsigned short* xab[2] = {(unsigned short*)(similar + 25690112),
                            (unsigned short*)(similar + 29884416)};
  unsigned short* xbb[2] = {(unsigned short*)(similar + 27787264),
                            (unsigned short*)(similar + 31981568)};
  // scratch in 'simil' region:
  unsigned short* wbuf = (unsigned short*)(simil + 33554432);
  const size_t WSZ = 559104;  // wqkv 44544 + wo 14848 + w1 262144 + w2 237568

  // d_ws layout for sim (bytes)
  unsigned char* ws = (unsigned char*)d_ws;
  unsigned short* feaT = (unsigned short*)ws;                   // 1,048,576 B
  unsigned short* simT = (unsigned short*)(ws + 1048576);       // 1,425,408 B
  float* fnb = (float*)(ws + 2473984);                          //    32,768 B
  float* snb = (float*)(ws + 2506752);                          //    44,544 B
  const bool ws_ok = ws_size >= 2551296;

  {
    ConvJobs J;
    int cum = 0;
    auto add = [&](int j, const float* s, unsigned short* dd, int R, int K,
                   int Kp, int mode) {
      J.src[j] = s; J.dst[j] = dd; J.K[j] = K; J.Kp[j] = Kp; J.mode[j] = mode;
      J.cum[j] = cum; cum += R * Kp;
    };
    add(0, x0, Ab, 32768, 116, 128, 0);
    for (int L = 0; L < 2; ++L) {
      unsigned short* wb = wbuf + L * WSZ;
      add(1 + L * 4, p[L * 12 + 0], wb + 0, 348, 116, 128, 0);
      add(2 + L * 4, p[L * 12 + 2], wb + 44544, 116, 116, 128, 1);  // wo spread
      add(3 + L * 4, p[L * 12 + 6], wb + 59392, 2048, 116, 128, 0);
      add(4 + L * 4, p[L * 12 + 8], wb + 321536, 116, 2048, 2048, 0);
    }
    J.cum[9] = cum;
    hipLaunchKernelGGL(convert_all_kernel, dim3(2048), dim3(256), 0, stream, J);
  }

  const unsigned short* Ain = Ab;
  const float* resin = x0;
  for (int L = 0; L < 2; ++L) {
    unsigned short* wb = wbuf + L * WSZ;
    const float* bqkv = p[L * 12 + 1];
    const float* bo = p[L * 12 + 3];
    const float* g1 = p[L * 12 + 4];
    const float* bn1 = p[L * 12 + 5];
    const float* b1 = p[L * 12 + 7];
    const float* b2 = p[L * 12 + 9];
    const float* g2 = p[L * 12 + 10];
    const float* bn2 = p[L * 12 + 11];

    // qkv -> head-major layout
    hipLaunchKernelGGL((mgemm_kernel<3>), dim3(256, 3), dim3(256), 0, stream,
                       Ain, wb + 0, bqkv, 348, 128, 0, qkvp);
    hipLaunchKernelGGL(attn_kernel, dim3(2048), dim3(64), 0, stream, qkvp,
                       obufb);
    // o-proj + res + LN (64-row tiles)
    hipLaunchKernelGGL(mgemm64_ln_kernel, dim3(512), dim3(256), 0, stream,
                       obufb, wb + 44544, bo, 128, xab[L], xa_f[L], resin, g1,
                       bn1);
    // fused FFN (hidden tensor stays in LDS)
    hipLaunchKernelGGL(ffn_fused_kernel, dim3(512), dim3(256), 0, stream,
                       xab[L], wb + 59392, b1, wb + 321536, b2, xa_f[L], g2,
                       bn2, xbb[L], xb_f[L]);
    Ain = xbb[L];
    resin = xb_f[L];
  }

  hipLaunchKernelGGL(fc_kernel, dim3(4, 64), dim3(256), 0, stream, xb_f[1],
                     fc_w, fc_b, fea);
  if (ws_ok) {
    hipLaunchKernelGGL(sim_prep_kernel, dim3(180), dim3(256), 0, stream, fea,
                       simin, feaT, simT, fnb, snb);
    hipLaunchKernelGGL(sim_mfma2_kernel, dim3(116, 64), dim3(256), 0, stream,
                       feaT, simT, fnb, snb, simil, similar);
  } else {
    hipLaunchKernelGGL(sim_mfma_kernel, dim3(116, 64), dim3(256), 0, stream,
                       fea, simin, simil, similar);
  }
}